// Round 11
// baseline (118.966 us; speedup 1.0000x reference)
//
#include <hip/hip_runtime.h>
#include <hip/hip_bf16.h>
#include <stdint.h>

#define N_ELx 768
#define EMBx 128
#define TPSx 64
#define EDGE_INx 32
#define EPB 256            // edges per block (4 waves x 64)
#define NBINS 2304         // 3 types * 768 receivers
#define NB_SORT 96

typedef __attribute__((ext_vector_type(8))) short bf16x8;
typedef __attribute__((ext_vector_type(4))) float f32x4;
typedef __attribute__((ext_vector_type(4))) uint32_t u32x4;
typedef __attribute__((ext_vector_type(2))) uint32_t u32x2;

__device__ __forceinline__ short f2bf(float f) {
    union { float f; uint32_t u; } v; v.f = f;
    uint32_t u = v.u;
    uint32_t r = (u + 0x7FFFu + ((u >> 16) & 1u)) >> 16;
    return (short)r;
}

// 1-instruction packed f32->bf16 pair (lo -> low16, hi -> high16), RNE
__device__ __forceinline__ uint32_t cvtpk(float lo, float hi) {
    uint32_t r;
    asm("v_cvt_pk_bf16_f32 %0, %1, %2" : "=v"(r) : "v"(lo), "v"(hi));
    return r;
}

__device__ __forceinline__ bf16x8 mk8(uint32_t a, uint32_t b, uint32_t c, uint32_t d) {
    union { u32x4 u; bf16x8 h; } x;
    x.u = (u32x4){a, b, c, d};
    return x.h;
}

// fast silu: avoids fp32 div sequence
__device__ __forceinline__ float silu_f(float x) {
    float e = __builtin_amdgcn_exp2f(-1.442695041f * x);
    return x * __builtin_amdgcn_rcpf(1.0f + e);
}

// ---------------- setup kernel: prep (blocks 0..13) + blockhist (14..109) ----
__global__ __launch_bounds__(256)
void setup_kernel(const float* __restrict__ elec, const float* __restrict__ nuclei,
                  const float* __restrict__ uW, const float* __restrict__ wW,
                  const float* __restrict__ hWee, const float* __restrict__ hbee,
                  const float* __restrict__ hWne, const float* __restrict__ hbne,
                  float* __restrict__ hx0, float* __restrict__ hx1, float* __restrict__ hxn,
                  short* __restrict__ ufragT, short* __restrict__ wWfrag,
                  const int* __restrict__ r0, const int* __restrict__ r1,
                  const int* __restrict__ r2,
                  int n0, int n1, int n2, int* __restrict__ blockHist,
                  float* __restrict__ z)
{
    __shared__ __align__(16) char smem[32768];
    int b = blockIdx.x;
    int tid = threadIdx.x;
    if (b < 12) {
        short* lds_a = (short*)smem;   // [kk*4+kc][row][8]
        int t = b / 6, rb = b % 6;
        const float* W = hWee + t * (128 * 64);
        {
            int row = tid >> 1, half = tid & 1;
            const float4* src = (const float4*)(elec + (size_t)(rb * 128 + row) * 128 + half * 64);
            #pragma unroll
            for (int c = 0; c < 8; ++c) {
                float4 fa = src[c * 2 + 0], fb = src[c * 2 + 1];
                bf16x8 v;
                v[0] = f2bf(fa.x); v[1] = f2bf(fa.y); v[2] = f2bf(fa.z); v[3] = f2bf(fa.w);
                v[4] = f2bf(fb.x); v[5] = f2bf(fb.y); v[6] = f2bf(fb.z); v[7] = f2bf(fb.w);
                int kk = half * 2 + (c >> 2), kc = c & 3;
                *(bf16x8*)&lds_a[((kk * 4 + kc) * 128 + row) * 8] = v;
            }
        }
        __syncthreads();
        int lane = tid & 63, w = tid >> 6, kc = lane >> 4, cr = lane & 15;
        int col = w * 16 + cr;
        bf16x8 bfrag[4];
        #pragma unroll
        for (int kk = 0; kk < 4; ++kk) {
            bf16x8 v;
            #pragma unroll
            for (int j = 0; j < 8; ++j)
                v[j] = f2bf(W[(kk * 32 + kc * 8 + j) * 64 + col]);
            bfrag[kk] = v;
        }
        float bias = hbee[t * 64 + col];
        float* dst = (t == 0 ? hx0 : hx1);
        f32x4 zero4 = {0.f, 0.f, 0.f, 0.f};
        #pragma unroll
        for (int rt = 0; rt < 8; ++rt) {
            f32x4 acc = zero4;
            #pragma unroll
            for (int kk = 0; kk < 4; ++kk) {
                bf16x8 a = *(const bf16x8*)&lds_a[((kk * 4 + kc) * 128 + rt * 16 + cr) * 8];
                acc = __builtin_amdgcn_mfma_f32_16x16x32_bf16(a, bfrag[kk], acc, 0, 0, 0);
            }
            #pragma unroll
            for (int r = 0; r < 4; ++r) {
                int row = rb * 128 + rt * 16 + kc * 4 + r;
                dst[row * 64 + col] = silu_f(acc[r] + bias);
            }
        }
    } else if (b == 12) {
        // hxn: silu(nuclei @ hWne + hbne), 32x64 @ 64x64 (tiny, scalar)
        int lr = tid >> 6, col = tid & 63;
        for (int i = 0; i < 8; ++i) {
            int row = lr * 8 + i;
            float acc = 0.f;
            for (int k = 0; k < 64; ++k)
                acc += nuclei[row * 64 + k] * hWne[k * 64 + col];
            hxn[row * 64 + col] = silu_f(acc + hbne[col]);
        }
    } else if (b == 13) {
        // ufragT: A-fragment of uW^T: A[ucol=tr*16+cr][k=featcol=lg*8+j]
        for (int idx = tid; idx < 3 * 4 * 64; idx += 256) {
            int lane = idx & 63, tr = (idx >> 6) & 3, ty = idx >> 8;
            int lg = lane >> 4, cr = lane & 15;
            for (int j = 0; j < 8; ++j)
                ufragT[idx * 8 + j] =
                    f2bf(uW[(ty * EDGE_INx + lg * 8 + j) * TPSx + tr * 16 + cr]);
        }
        // wWfrag: B-fragment of wW: B[k=ks*32+lg*8+j][col=tn*16+cr]
        for (int idx = tid; idx < 3 * 2 * 4 * 64; idx += 256) {
            int lane = idx & 63, ct = (idx >> 6) & 3, ks = (idx >> 8) & 1, ty = idx >> 9;
            for (int j = 0; j < 8; ++j) {
                int k = ks * 32 + (lane >> 4) * 8 + j, col = ct * 16 + (lane & 15);
                wWfrag[idx * 8 + j] = f2bf(wW[(ty * 64 + k) * 64 + col]);
            }
        }
    } else {
        // blockhist for sort + fold-in z zeroing
        int* h = (int*)smem;
        int bb = b - 14;
        for (int i = bb * 256 + tid; i < 3 * N_ELx * TPSx; i += NB_SORT * 256)
            z[i] = 0.f;
        for (int i = tid; i < NBINS; i += 256) h[i] = 0;
        __syncthreads();
        int total = n0 + n1 + n2;
        int chunk = (total + NB_SORT - 1) / NB_SORT;
        int start = bb * chunk, end = min(start + chunk, total);
        for (int i = start + tid; i < end; i += 256) {
            int t, j;
            if (i < n0)            { t = 0; j = i; }
            else if (i < n0 + n1)  { t = 1; j = i - n0; }
            else                   { t = 2; j = i - n0 - n1; }
            int rv = (t == 0 ? r0 : (t == 1 ? r1 : r2))[j];
            atomicAdd(&h[t * 768 + rv], 1);
        }
        __syncthreads();
        for (int i = tid; i < NBINS; i += 256)
            blockHist[i * NB_SORT + bb] = h[i];
    }
}

// ---------------- sort: wave-per-bin parallel scan, then scatter -------------
__global__ __launch_bounds__(256)
void binscan_kernel(int* __restrict__ blockHist, int* __restrict__ binTotal)
{
    int tid = threadIdx.x;
    int w = tid >> 6, lane = tid & 63;
    int bin = blockIdx.x * 4 + w;            // grid = NBINS/4 = 576
    int* p = blockHist + bin * NB_SORT;      // 96 entries
    int a = p[lane];
    int bv = (lane < 32) ? p[64 + lane] : 0;
    int a0 = a, b0 = bv;
    #pragma unroll
    for (int d = 1; d < 64; d <<= 1) {
        int tv = __shfl_up(a, d, 64);
        if (lane >= d) a += tv;
    }
    int sumA = __shfl(a, 63, 64);
    #pragma unroll
    for (int d = 1; d < 32; d <<= 1) {
        int tv = __shfl_up(bv, d, 64);
        if (lane >= d) bv += tv;
    }
    p[lane] = a - a0;                        // exclusive
    if (lane < 32) p[64 + lane] = sumA + bv - b0;
    if (lane == 31) binTotal[bin] = sumA + bv;
}

__global__ __launch_bounds__(256)
void scatter2_kernel(const int* __restrict__ r0, const int* __restrict__ r1,
                     const int* __restrict__ r2,
                     int n0, int n1, int n2,
                     const int* __restrict__ blockHist,
                     const int* __restrict__ binTotal,
                     int* __restrict__ perm)
{
    __shared__ int cursor[NBINS];
    __shared__ int part[256];
    int tid = threadIdx.x, b = blockIdx.x;
    int l[9]; int s = 0;
    #pragma unroll
    for (int j = 0; j < 9; ++j) { l[j] = binTotal[tid * 9 + j]; s += l[j]; }
    part[tid] = s;
    __syncthreads();
    for (int off = 1; off < 256; off <<= 1) {
        int v = (tid >= off) ? part[tid - off] : 0;
        __syncthreads();
        part[tid] += v;
        __syncthreads();
    }
    int run = (tid == 0) ? 0 : part[tid - 1];
    #pragma unroll
    for (int j = 0; j < 9; ++j) {
        int bin = tid * 9 + j;
        cursor[bin] = run + blockHist[bin * NB_SORT + b];
        run += l[j];
    }
    __syncthreads();
    int total = n0 + n1 + n2;
    int chunk = (total + NB_SORT - 1) / NB_SORT;
    int start = b * chunk, end = min(start + chunk, total);
    for (int i = start + tid; i < end; i += 256) {
        int t, j;
        if (i < n0)            { t = 0; j = i; }
        else if (i < n0 + n1)  { t = 1; j = i - n0; }
        else                   { t = 2; j = i - n0 - n1; }
        int rv = (t == 0 ? r0 : (t == 1 ? r1 : r2))[j];
        int pos = atomicAdd(&cursor[t * 768 + rv], 1);
        perm[pos] = j;
    }
}

// ---------------- edge kernel: LDS-staged weights, 4 waves/SIMD --------------
// Weights (uf/wf fragments) staged once per block into LDS and re-read per
// tile via ds_read_b128 — frees ~48 VGPRs so >=4 waves/SIMD stay resident.
__global__ __launch_bounds__(256, 4)
void edge_kernel(const float* __restrict__ feat0, const float* __restrict__ feat1,
                 const float* __restrict__ feat2,
                 const int* __restrict__ s0, const int* __restrict__ s1, const int* __restrict__ s2,
                 const int* __restrict__ r0, const int* __restrict__ r1, const int* __restrict__ r2,
                 const float* __restrict__ u_b, const float* __restrict__ w_b,
                 const float* __restrict__ hx0, const float* __restrict__ hx1,
                 const float* __restrict__ hxn,
                 const short* __restrict__ ufragT, const short* __restrict__ wWfrag,
                 const int* __restrict__ perm,
                 float* __restrict__ z,
                 int n0, int n1, int n2, int nb0, int nb1)
{
    __shared__ __align__(16) short wt_lds[(4 + 8) * 64 * 8];   // uf 4KB | wf 8KB
    __shared__ __align__(16) char ebuf_all[4][16 * 144];       // 2304B per wave

    int b = blockIdx.x;
    int t; const float* feat; const int* sn; const int* rc; const float* hx; int nE;
    if (b < nb0)            { t = 0; feat = feat0; sn = s0; rc = r0; hx = hx0; nE = n0; }
    else if (b < nb0 + nb1) { t = 1; b -= nb0; feat = feat1; sn = s1; rc = r1; hx = hx1; nE = n1; }
    else                    { t = 2; b -= nb0 + nb1; feat = feat2; sn = s2; rc = r2; hx = hxn; nE = n2; }

    int tid = threadIdx.x;
    int w = tid >> 6, lane = tid & 63, lg = lane >> 4, cr = lane & 15;
    int ebase = b * EPB + w * 64;

    // stage weight fragments (shared by the block's 4 waves)
    {
        const short* usrc = ufragT + t * (4 * 64 * 8);
        *(bf16x8*)&wt_lds[tid * 8] = *(const bf16x8*)&usrc[tid * 8];
        const short* wsrc = wWfrag + t * (2 * 4 * 64 * 8);
        *(bf16x8*)&wt_lds[(256 + tid) * 8] = *(const bf16x8*)&wsrc[tid * 8];
        *(bf16x8*)&wt_lds[(512 + tid) * 8] = *(const bf16x8*)&wsrc[(256 + tid) * 8];
    }
    __syncthreads();
    if (ebase >= nE) return;                    // empty wave (no barriers after)
    bool partial = (ebase + 64 > nE);           // never true: all counts divide 256
    char* ebuf = ebuf_all[w];
    int t_off = (t == 0) ? 0 : (t == 1 ? n0 : n0 + n1);
    float* zt = z + t * (N_ELx * TPSx);

    // biases stay in registers (20 regs)
    float4 ubv[4];
    #pragma unroll
    for (int tr = 0; tr < 4; ++tr)
        ubv[tr] = *(const float4*)(u_b + t * 64 + tr * 16 + lg * 4);
    float wbv[4];
    #pragma unroll
    for (int tn = 0; tn < 4; ++tn)
        wbv[tn] = w_b[t * 64 + tn * 16 + cr];

    // own-edge meta: lane owns edge ebase + lane
    int e_own = ebase + lane;
    int pe_own = perm[t_off + min(e_own, nE - 1)];
    int s_own = sn[pe_own];
    int r_own = rc[pe_own];

    f32x4 zero4 = {0.f, 0.f, 0.f, 0.f};

    // deferred segment accumulator: per-lane partials, flushed on receiver change
    float accv[4] = {0.f, 0.f, 0.f, 0.f};
    int curR = -1;
    auto flush = [&]() {
        if (curR >= 0) {
            #pragma unroll
            for (int tn = 0; tn < 4; ++tn) {
                float v = accv[tn];
                v += __shfl_xor(v, 16, 64);
                v += __shfl_xor(v, 32, 64);
                if (lg == 0) atomicAdd(&zt[curR * 64 + tn * 16 + cr], v);
                accv[tn] = 0.f;
            }
        }
    };

    // ---- prologue: prefetch feat for tile 0 ----
    int pF_n = __shfl(pe_own, cr, 64);
    float4 fa_n, fc_n;
    {
        const float4* fp = (const float4*)(feat + (size_t)pF_n * EDGE_INx + lg * 8);
        fa_n = fp[0]; fc_n = fp[1];
    }

    #pragma unroll 2
    for (int tc = 0; tc < 4; ++tc) {
        int b16 = tc * 16;
        float4 fa = fa_n, fc = fc_n;

        // ---- prefetch feat for tile tc+1 ----
        if (tc < 3) {
            pF_n = __shfl(pe_own, (tc + 1) * 16 + cr, 64);
            const float4* fp = (const float4*)(feat + (size_t)pF_n * EDGE_INx + lg * 8);
            fa_n = fp[0]; fc_n = fp[1];
        }

        // ---- per-tile meta via shfl; issue hx gathers early ----
        int sidv[4];
        #pragma unroll
        for (int r = 0; r < 4; ++r)
            sidv[r] = __shfl(s_own, b16 + lg * 4 + r, 64);
        int rF = __shfl(r_own, b16, 64);
        int rL = __shfl(r_own, b16 + 15, 64);

        float hv[4][4];   // [tn][r] — issued here, consumed after GEMM2
        if (!partial) {
            #pragma unroll
            for (int r = 0; r < 4; ++r) {
                const float* hp = hx + sidv[r] * TPSx + cr;
                #pragma unroll
                for (int tn = 0; tn < 4; ++tn)
                    hv[tn][r] = hp[tn * 16];
            }
        } else {
            #pragma unroll
            for (int r = 0; r < 4; ++r) {
                bool aE = (ebase + b16 + lg * 4 + r) < nE;
                const float* hp = hx + sidv[r] * TPSx + cr;
                #pragma unroll
                for (int tn = 0; tn < 4; ++tn)
                    hv[tn][r] = aE ? hp[tn * 16] : 0.f;
            }
        }

        // ---- feat B-frag from prefetched regs ----
        bf16x8 fB = mk8(cvtpk(fa.x, fa.y), cvtpk(fa.z, fa.w),
                        cvtpk(fc.x, fc.y), cvtpk(fc.z, fc.w));

        // ---- GEMM1: e^T tiles (uf fragments re-read from LDS) ----
        f32x4 d1[4];
        #pragma unroll
        for (int tr = 0; tr < 4; ++tr) {
            bf16x8 a = *(const bf16x8*)&wt_lds[(tr * 64 + lane) * 8];
            d1[tr] = __builtin_amdgcn_mfma_f32_16x16x32_bf16(a, fB, zero4, 0, 0, 0);
        }

        // ---- silu + pack + per-wave LDS transpose write ----
        #pragma unroll
        for (int tr = 0; tr < 4; ++tr) {
            float v0 = silu_f(d1[tr][0] + ubv[tr].x);
            float v1 = silu_f(d1[tr][1] + ubv[tr].y);
            float v2 = silu_f(d1[tr][2] + ubv[tr].z);
            float v3 = silu_f(d1[tr][3] + ubv[tr].w);
            u32x2 pk; pk[0] = cvtpk(v0, v1); pk[1] = cvtpk(v2, v3);
            *(u32x2*)(ebuf + cr * 144 + tr * 32 + lg * 8) = pk;
        }

        // ---- read A-frags of e (same-wave DS ordering: no barrier) ----
        bf16x8 ebf0 = *(const bf16x8*)(ebuf + cr * 144 + 0 * 64 + lg * 16);
        bf16x8 ebf1 = *(const bf16x8*)(ebuf + cr * 144 + 1 * 64 + lg * 16);

        // ---- GEMM2: we tiles (wf fragments re-read from LDS) ----
        f32x4 d2[4];
        #pragma unroll
        for (int tn = 0; tn < 4; ++tn) {
            bf16x8 w0 = *(const bf16x8*)&wt_lds[(256 + (0 * 4 + tn) * 64 + lane) * 8];
            bf16x8 w1 = *(const bf16x8*)&wt_lds[(256 + (1 * 4 + tn) * 64 + lane) * 8];
            f32x4 acc = __builtin_amdgcn_mfma_f32_16x16x32_bf16(ebf0, w0, zero4, 0, 0, 0);
            d2[tn] = __builtin_amdgcn_mfma_f32_16x16x32_bf16(ebf1, w1, acc, 0, 0, 0);
        }

        // ---- message values ----
        float m[4][4];   // [tn][r]
        #pragma unroll
        for (int tn = 0; tn < 4; ++tn)
            #pragma unroll
            for (int r = 0; r < 4; ++r)
                m[tn][r] = silu_f(d2[tn][r] + wbv[tn]) * hv[tn][r];

        // ---- segment handling: accumulate in regs, flush on receiver change ----
        if (rF == rL) {
            if (rF != curR) { flush(); curR = rF; }
            #pragma unroll
            for (int tn = 0; tn < 4; ++tn)
                accv[tn] += (m[tn][0] + m[tn][1]) + (m[tn][2] + m[tn][3]);
        } else {
            flush();
            curR = -1;
            int ridv[4];
            #pragma unroll
            for (int r = 0; r < 4; ++r)
                ridv[r] = __shfl(r_own, b16 + lg * 4 + r, 64);
            float a0 = m[0][0], a1 = m[1][0], a2 = m[2][0], a3 = m[3][0];
            int segR = ridv[0];
            #pragma unroll
            for (int r = 1; r < 4; ++r) {
                if (ridv[r] != segR) {
                    atomicAdd(&zt[segR * 64 +  0 + cr], a0);
                    atomicAdd(&zt[segR * 64 + 16 + cr], a1);
                    atomicAdd(&zt[segR * 64 + 32 + cr], a2);
                    atomicAdd(&zt[segR * 64 + 48 + cr], a3);
                    a0 = m[0][r]; a1 = m[1][r]; a2 = m[2][r]; a3 = m[3][r];
                    segR = ridv[r];
                } else {
                    a0 += m[0][r]; a1 += m[1][r]; a2 += m[2][r]; a3 += m[3][r];
                }
            }
            atomicAdd(&zt[segR * 64 +  0 + cr], a0);
            atomicAdd(&zt[segR * 64 + 16 + cr], a1);
            atomicAdd(&zt[segR * 64 + 32 + cr], a2);
            atomicAdd(&zt[segR * 64 + 48 + cr], a3);
        }
    }
    flush();
}

// ---------------- final kernel: g-subnets + residual ----------------
__global__ __launch_bounds__(128)
void final_kernel(const float* __restrict__ elec, const float* __restrict__ z,
                  const float* __restrict__ gWres, const float* __restrict__ gbres,
                  const float* __restrict__ gWz, const float* __restrict__ gbz,
                  float* __restrict__ out)
{
    __shared__ float xe[4 * 128];
    __shared__ float xz[3 * 4 * 64];
    int b = blockIdx.x;
    int tid = threadIdx.x;
    int row0 = b * 4;
    for (int i = tid; i < 4 * 128; i += 128)
        xe[i] = elec[row0 * 128 + i];
    for (int i = tid; i < 3 * 4 * 64; i += 128) {
        int t = i >> 8; int rr = (i >> 6) & 3; int k = i & 63;
        xz[i] = z[t * N_ELx * 64 + (row0 + rr) * 64 + k];
    }
    __syncthreads();

    int col = tid;
    float accr[4] = {0.f, 0.f, 0.f, 0.f};
    for (int k = 0; k < 128; ++k) {
        float wv = gWres[k * 128 + col];
        #pragma unroll
        for (int r = 0; r < 4; ++r) accr[r] += xe[r * 128 + k] * wv;
    }
    float o[4];
    float br = gbres[col];
    #pragma unroll
    for (int r = 0; r < 4; ++r) o[r] = silu_f(accr[r] + br) + xe[r * 128 + col];

    for (int t = 0; t < 3; ++t) {
        float accz[4] = {0.f, 0.f, 0.f, 0.f};
        for (int k = 0; k < 64; ++k) {
            float wv = gWz[(t * 64 + k) * 128 + col];
            #pragma unroll
            for (int r = 0; r < 4; ++r) accz[r] += xz[t * 256 + r * 64 + k] * wv;
        }
        float bz = gbz[t * 128 + col];
        #pragma unroll
        for (int r = 0; r < 4; ++r) o[r] += silu_f(accz[r] + bz);
    }
    #pragma unroll
    for (int r = 0; r < 4; ++r) out[(row0 + r) * 128 + col] = o[r];
}

extern "C" void kernel_launch(void* const* d_in, const int* in_sizes, int n_in,
                              void* d_out, int out_size, void* d_ws, size_t ws_size,
                              hipStream_t stream)
{
    const float* elec   = (const float*)d_in[0];
    const float* nuclei = (const float*)d_in[1];
    const float* feat0  = (const float*)d_in[2];
    const float* feat1  = (const float*)d_in[3];
    const float* feat2  = (const float*)d_in[4];
    const int*   s0     = (const int*)d_in[5];
    const int*   r0     = (const int*)d_in[6];
    const int*   s1     = (const int*)d_in[7];
    const int*   r1     = (const int*)d_in[8];
    const int*   s2     = (const int*)d_in[9];
    const int*   r2     = (const int*)d_in[10];
    const float* u_W    = (const float*)d_in[11];
    const float* u_b    = (const float*)d_in[12];
    const float* w_W    = (const float*)d_in[13];
    const float* w_b    = (const float*)d_in[14];
    const float* hWee   = (const float*)d_in[15];
    const float* hbee   = (const float*)d_in[16];
    const float* hWne   = (const float*)d_in[17];
    const float* hbne   = (const float*)d_in[18];
    const float* gWres  = (const float*)d_in[19];
    const float* gbres  = (const float*)d_in[20];
    const float* gWz    = (const float*)d_in[21];
    const float* gbz    = (const float*)d_in[22];
    float* out = (float*)d_out;

    char* ws = (char*)d_ws;
    float* hx0      = (float*)(ws + 0);           // 196608
    float* hx1      = (float*)(ws + 196608);      // 196608
    float* hxn      = (float*)(ws + 393216);      // 8192
    float* z        = (float*)(ws + 401408);      // 589824
    short* ufragT   = (short*)(ws + 991232);      // 12288
    short* wWfrag   = (short*)(ws + 1003520);     // 24576
    int*   binTotal = (int*)(ws + 1028096);       // 9216
    int*   perm     = (int*)(ws + 1046528);       // 2454528
    int*   blockHist= (int*)(ws + 3501056);       // 884736  (end: 4385792)

    int n0 = in_sizes[2] / EDGE_INx;
    int n1 = in_sizes[3] / EDGE_INx;
    int n2 = in_sizes[4] / EDGE_INx;
    int nb0 = (n0 + EPB - 1) / EPB;
    int nb1 = (n1 + EPB - 1) / EPB;
    int nb2 = (n2 + EPB - 1) / EPB;

    setup_kernel<<<14 + NB_SORT, 256, 0, stream>>>(
        elec, nuclei, u_W, w_W, hWee, hbee, hWne, hbne,
        hx0, hx1, hxn, ufragT, wWfrag,
        r0, r1, r2, n0, n1, n2, blockHist, z);
    binscan_kernel<<<NBINS / 4, 256, 0, stream>>>(blockHist, binTotal);
    scatter2_kernel<<<NB_SORT, 256, 0, stream>>>(r0, r1, r2, n0, n1, n2,
                                                 blockHist, binTotal, perm);
    edge_kernel<<<nb0 + nb1 + nb2, 256, 0, stream>>>(
        feat0, feat1, feat2, s0, s1, s2, r0, r1, r2,
        u_b, w_b, hx0, hx1, hxn, ufragT, wWfrag, perm, z,
        n0, n1, n2, nb0, nb1);
    final_kernel<<<192, 128, 0, stream>>>(elec, z, gWres, gbres, gWz, gbz, out);
}

// Round 12
// 104.564 us; speedup vs baseline: 1.1377x; 1.1377x over previous
//
#include <hip/hip_runtime.h>
#include <hip/hip_bf16.h>
#include <stdint.h>

#define N_ELx 768
#define EMBx 128
#define TPSx 64
#define EDGE_INx 32
#define EPB 256            // edges per block (4 waves x 64)
#define NBINS 2304         // 3 types * 768 receivers
#define NB_SORT 96
#define SETUP_FIXED 110    // 14 prep + 96 hist blocks in setup_kernel

typedef __attribute__((ext_vector_type(8))) short bf16x8;
typedef __attribute__((ext_vector_type(4))) float f32x4;
typedef __attribute__((ext_vector_type(4))) uint32_t u32x4;
typedef __attribute__((ext_vector_type(2))) uint32_t u32x2;

__device__ __forceinline__ short f2bf(float f) {
    union { float f; uint32_t u; } v; v.f = f;
    uint32_t u = v.u;
    uint32_t r = (u + 0x7FFFu + ((u >> 16) & 1u)) >> 16;
    return (short)r;
}

// 1-instruction packed f32->bf16 pair (lo -> low16, hi -> high16), RNE
__device__ __forceinline__ uint32_t cvtpk(float lo, float hi) {
    uint32_t r;
    asm("v_cvt_pk_bf16_f32 %0, %1, %2" : "=v"(r) : "v"(lo), "v"(hi));
    return r;
}

__device__ __forceinline__ bf16x8 mk8(uint32_t a, uint32_t b, uint32_t c, uint32_t d) {
    union { u32x4 u; bf16x8 h; } x;
    x.u = (u32x4){a, b, c, d};
    return x.h;
}

// fast silu: avoids fp32 div sequence
__device__ __forceinline__ float silu_f(float x) {
    float e = __builtin_amdgcn_exp2f(-1.442695041f * x);
    return x * __builtin_amdgcn_rcpf(1.0f + e);
}

// ------- setup kernel: prep (0..13) + blockhist (14..109) + feat->bf16 ------
__global__ __launch_bounds__(256)
void setup_kernel(const float* __restrict__ elec, const float* __restrict__ nuclei,
                  const float* __restrict__ uW, const float* __restrict__ wW,
                  const float* __restrict__ hWee, const float* __restrict__ hbee,
                  const float* __restrict__ hWne, const float* __restrict__ hbne,
                  float* __restrict__ hx0, float* __restrict__ hx1, float* __restrict__ hxn,
                  short* __restrict__ ufragT, short* __restrict__ wWfrag,
                  const int* __restrict__ r0, const int* __restrict__ r1,
                  const int* __restrict__ r2,
                  const float* __restrict__ feat0, const float* __restrict__ feat1,
                  const float* __restrict__ feat2, short* __restrict__ featbf,
                  int n0, int n1, int n2, int nc0, int nc1,
                  int* __restrict__ blockHist, float* __restrict__ z)
{
    __shared__ __align__(16) char smem[32768];
    int b = blockIdx.x;
    int tid = threadIdx.x;
    if (b >= SETUP_FIXED) {
        // feat -> bf16 conversion (linear, coalesced). One block = 1024 float4s.
        int cb = b - SETUP_FIXED;
        const float* src; short* dst; int fb4;
        if (cb < nc0)            { src = feat0; dst = featbf;                    fb4 = cb; }
        else if (cb < nc0 + nc1) { src = feat1; dst = featbf + (size_t)n0 * 32;  fb4 = cb - nc0; }
        else                     { src = feat2; dst = featbf + (size_t)(n0 + n1) * 32; fb4 = cb - nc0 - nc1; }
        int i0 = fb4 * 1024;
        #pragma unroll
        for (int k = 0; k < 4; ++k) {
            int idx = i0 + k * 256 + tid;
            float4 v = ((const float4*)src)[idx];
            u32x2 o; o[0] = cvtpk(v.x, v.y); o[1] = cvtpk(v.z, v.w);
            *(u32x2*)(dst + (size_t)idx * 4) = o;
        }
        return;
    }
    if (b < 12) {
        short* lds_a = (short*)smem;   // [kk*4+kc][row][8]
        int t = b / 6, rb = b % 6;
        const float* W = hWee + t * (128 * 64);
        {
            int row = tid >> 1, half = tid & 1;
            const float4* src = (const float4*)(elec + (size_t)(rb * 128 + row) * 128 + half * 64);
            #pragma unroll
            for (int c = 0; c < 8; ++c) {
                float4 fa = src[c * 2 + 0], fb = src[c * 2 + 1];
                bf16x8 v;
                v[0] = f2bf(fa.x); v[1] = f2bf(fa.y); v[2] = f2bf(fa.z); v[3] = f2bf(fa.w);
                v[4] = f2bf(fb.x); v[5] = f2bf(fb.y); v[6] = f2bf(fb.z); v[7] = f2bf(fb.w);
                int kk = half * 2 + (c >> 2), kc = c & 3;
                *(bf16x8*)&lds_a[((kk * 4 + kc) * 128 + row) * 8] = v;
            }
        }
        __syncthreads();
        int lane = tid & 63, w = tid >> 6, kc = lane >> 4, cr = lane & 15;
        int col = w * 16 + cr;
        bf16x8 bfrag[4];
        #pragma unroll
        for (int kk = 0; kk < 4; ++kk) {
            bf16x8 v;
            #pragma unroll
            for (int j = 0; j < 8; ++j)
                v[j] = f2bf(W[(kk * 32 + kc * 8 + j) * 64 + col]);
            bfrag[kk] = v;
        }
        float bias = hbee[t * 64 + col];
        float* dst = (t == 0 ? hx0 : hx1);
        f32x4 zero4 = {0.f, 0.f, 0.f, 0.f};
        #pragma unroll
        for (int rt = 0; rt < 8; ++rt) {
            f32x4 acc = zero4;
            #pragma unroll
            for (int kk = 0; kk < 4; ++kk) {
                bf16x8 a = *(const bf16x8*)&lds_a[((kk * 4 + kc) * 128 + rt * 16 + cr) * 8];
                acc = __builtin_amdgcn_mfma_f32_16x16x32_bf16(a, bfrag[kk], acc, 0, 0, 0);
            }
            #pragma unroll
            for (int r = 0; r < 4; ++r) {
                int row = rb * 128 + rt * 16 + kc * 4 + r;
                dst[row * 64 + col] = silu_f(acc[r] + bias);
            }
        }
    } else if (b == 12) {
        // hxn: silu(nuclei @ hWne + hbne), 32x64 @ 64x64 (tiny, scalar)
        int lr = tid >> 6, col = tid & 63;
        for (int i = 0; i < 8; ++i) {
            int row = lr * 8 + i;
            float acc = 0.f;
            for (int k = 0; k < 64; ++k)
                acc += nuclei[row * 64 + k] * hWne[k * 64 + col];
            hxn[row * 64 + col] = silu_f(acc + hbne[col]);
        }
    } else if (b == 13) {
        // ufragT: A-fragment of uW^T: A[ucol=tr*16+cr][k=featcol=lg*8+j]
        for (int idx = tid; idx < 3 * 4 * 64; idx += 256) {
            int lane = idx & 63, tr = (idx >> 6) & 3, ty = idx >> 8;
            int lg = lane >> 4, cr = lane & 15;
            for (int j = 0; j < 8; ++j)
                ufragT[idx * 8 + j] =
                    f2bf(uW[(ty * EDGE_INx + lg * 8 + j) * TPSx + tr * 16 + cr]);
        }
        // wWfrag: B-fragment of wW: B[k=ks*32+lg*8+j][col=tn*16+cr]
        for (int idx = tid; idx < 3 * 2 * 4 * 64; idx += 256) {
            int lane = idx & 63, ct = (idx >> 6) & 3, ks = (idx >> 8) & 1, ty = idx >> 9;
            for (int j = 0; j < 8; ++j) {
                int k = ks * 32 + (lane >> 4) * 8 + j, col = ct * 16 + (lane & 15);
                wWfrag[idx * 8 + j] = f2bf(wW[(ty * 64 + k) * 64 + col]);
            }
        }
    } else {
        // blockhist for sort + fold-in z zeroing
        int* h = (int*)smem;
        int bb = b - 14;
        for (int i = bb * 256 + tid; i < 3 * N_ELx * TPSx; i += NB_SORT * 256)
            z[i] = 0.f;
        for (int i = tid; i < NBINS; i += 256) h[i] = 0;
        __syncthreads();
        int total = n0 + n1 + n2;
        int chunk = (total + NB_SORT - 1) / NB_SORT;
        int start = bb * chunk, end = min(start + chunk, total);
        for (int i = start + tid; i < end; i += 256) {
            int t, j;
            if (i < n0)            { t = 0; j = i; }
            else if (i < n0 + n1)  { t = 1; j = i - n0; }
            else                   { t = 2; j = i - n0 - n1; }
            int rv = (t == 0 ? r0 : (t == 1 ? r1 : r2))[j];
            atomicAdd(&h[t * 768 + rv], 1);
        }
        __syncthreads();
        for (int i = tid; i < NBINS; i += 256)
            blockHist[i * NB_SORT + bb] = h[i];
    }
}

// ---------------- sort: wave-per-bin parallel scan, then scatter -------------
__global__ __launch_bounds__(256)
void binscan_kernel(int* __restrict__ blockHist, int* __restrict__ binTotal)
{
    int tid = threadIdx.x;
    int w = tid >> 6, lane = tid & 63;
    int bin = blockIdx.x * 4 + w;            // grid = NBINS/4 = 576
    int* p = blockHist + bin * NB_SORT;      // 96 entries
    int a = p[lane];
    int bv = (lane < 32) ? p[64 + lane] : 0;
    int a0 = a, b0 = bv;
    #pragma unroll
    for (int d = 1; d < 64; d <<= 1) {
        int tv = __shfl_up(a, d, 64);
        if (lane >= d) a += tv;
    }
    int sumA = __shfl(a, 63, 64);
    #pragma unroll
    for (int d = 1; d < 32; d <<= 1) {
        int tv = __shfl_up(bv, d, 64);
        if (lane >= d) bv += tv;
    }
    p[lane] = a - a0;                        // exclusive
    if (lane < 32) p[64 + lane] = sumA + bv - b0;
    if (lane == 31) binTotal[bin] = sumA + bv;
}

__global__ __launch_bounds__(256)
void scatter2_kernel(const int* __restrict__ r0, const int* __restrict__ r1,
                     const int* __restrict__ r2,
                     int n0, int n1, int n2,
                     const int* __restrict__ blockHist,
                     const int* __restrict__ binTotal,
                     int* __restrict__ perm)
{
    __shared__ int cursor[NBINS];
    __shared__ int part[256];
    int tid = threadIdx.x, b = blockIdx.x;
    int l[9]; int s = 0;
    #pragma unroll
    for (int j = 0; j < 9; ++j) { l[j] = binTotal[tid * 9 + j]; s += l[j]; }
    part[tid] = s;
    __syncthreads();
    for (int off = 1; off < 256; off <<= 1) {
        int v = (tid >= off) ? part[tid - off] : 0;
        __syncthreads();
        part[tid] += v;
        __syncthreads();
    }
    int run = (tid == 0) ? 0 : part[tid - 1];
    #pragma unroll
    for (int j = 0; j < 9; ++j) {
        int bin = tid * 9 + j;
        cursor[bin] = run + blockHist[bin * NB_SORT + b];
        run += l[j];
    }
    __syncthreads();
    int total = n0 + n1 + n2;
    int chunk = (total + NB_SORT - 1) / NB_SORT;
    int start = b * chunk, end = min(start + chunk, total);
    for (int i = start + tid; i < end; i += 256) {
        int t, j;
        if (i < n0)            { t = 0; j = i; }
        else if (i < n0 + n1)  { t = 1; j = i - n0; }
        else                   { t = 2; j = i - n0 - n1; }
        int rv = (t == 0 ? r0 : (t == 1 ? r1 : r2))[j];
        int pos = atomicAdd(&cursor[t * 768 + rv], 1);
        perm[pos] = j;
    }
}

// ---------------- edge kernel: 64 edges/wave, per-wave LDS transpose ---------
// BF16F=true: feat pre-converted to bf16 (64B rows); one ushort8 gather/lane
// per tile, prefetch depth 2 (full unroll). BF16F=false: R10 fp32 path.
template <bool BF16F>
__global__ __launch_bounds__(256)
void edge_kernel(const float* __restrict__ feat0, const float* __restrict__ feat1,
                 const float* __restrict__ feat2, const short* __restrict__ featbf,
                 const int* __restrict__ s0, const int* __restrict__ s1, const int* __restrict__ s2,
                 const int* __restrict__ r0, const int* __restrict__ r1, const int* __restrict__ r2,
                 const float* __restrict__ u_b, const float* __restrict__ w_b,
                 const float* __restrict__ hx0, const float* __restrict__ hx1,
                 const float* __restrict__ hxn,
                 const short* __restrict__ ufragT, const short* __restrict__ wWfrag,
                 const int* __restrict__ perm,
                 float* __restrict__ z,
                 int n0, int n1, int n2, int nb0, int nb1)
{
    __shared__ __align__(16) char ebuf_all[4][16 * 144];   // 2304B per wave

    int b = blockIdx.x;
    int t; const float* feat; const int* sn; const int* rc; const float* hx; int nE;
    if (b < nb0)            { t = 0; feat = feat0; sn = s0; rc = r0; hx = hx0; nE = n0; }
    else if (b < nb0 + nb1) { t = 1; b -= nb0; feat = feat1; sn = s1; rc = r1; hx = hx1; nE = n1; }
    else                    { t = 2; b -= nb0 + nb1; feat = feat2; sn = s2; rc = r2; hx = hxn; nE = n2; }

    int tid = threadIdx.x;
    int w = tid >> 6, lane = tid & 63, lg = lane >> 4, cr = lane & 15;
    int ebase = b * EPB + w * 64;
    if (ebase >= nE) return;                    // fully-empty wave (no barriers used)
    bool partial = (ebase + 64 > nE);           // never true: all counts divide 256
    char* ebuf = ebuf_all[w];
    int t_off = (t == 0) ? 0 : (t == 1 ? n0 : n0 + n1);
    const short* fbT = featbf + (size_t)t_off * 32;
    float* zt = z + t * (N_ELx * TPSx);

    // weight fragments + biases (L2-hot broadcast loads)
    bf16x8 uf[4];
    #pragma unroll
    for (int tr = 0; tr < 4; ++tr)
        uf[tr] = *(const bf16x8*)(ufragT + ((t * 4 + tr) * 64 + lane) * 8);
    bf16x8 wf[4][2];
    #pragma unroll
    for (int tn = 0; tn < 4; ++tn)
        #pragma unroll
        for (int ks = 0; ks < 2; ++ks)
            wf[tn][ks] = *(const bf16x8*)(wWfrag + (((t * 2 + ks) * 4 + tn) * 64 + lane) * 8);
    float4 ubv[4];
    #pragma unroll
    for (int tr = 0; tr < 4; ++tr)
        ubv[tr] = *(const float4*)(u_b + t * 64 + tr * 16 + lg * 4);
    float wbv[4];
    #pragma unroll
    for (int tn = 0; tn < 4; ++tn)
        wbv[tn] = w_b[t * 64 + tn * 16 + cr];

    // own-edge meta: lane owns edge ebase + lane
    int e_own = ebase + lane;
    int pe_own = perm[t_off + min(e_own, nE - 1)];
    int s_own = sn[pe_own];
    int r_own = rc[pe_own];

    f32x4 zero4 = {0.f, 0.f, 0.f, 0.f};

    // deferred segment accumulator
    float accv[4] = {0.f, 0.f, 0.f, 0.f};
    int curR = -1;
    auto flush = [&]() {
        if (curR >= 0) {
            #pragma unroll
            for (int tn = 0; tn < 4; ++tn) {
                float v = accv[tn];
                v += __shfl_xor(v, 16, 64);
                v += __shfl_xor(v, 32, 64);
                if (lg == 0) atomicAdd(&zt[curR * 64 + tn * 16 + cr], v);
                accv[tn] = 0.f;
            }
        }
    };

    // ---- feat prefetch ----
    int pFa[4];
    #pragma unroll
    for (int tc = 0; tc < 4; ++tc)
        pFa[tc] = __shfl(pe_own, tc * 16 + cr, 64);

    bf16x8 fbv[4];         // bf16 path (depth-2 rotation via full unroll)
    float4 fa_n, fc_n;     // fp32 path (depth-1)
    if constexpr (BF16F) {
        fbv[0] = *(const bf16x8*)(fbT + (size_t)pFa[0] * 32 + lg * 8);
        fbv[1] = *(const bf16x8*)(fbT + (size_t)pFa[1] * 32 + lg * 8);
    } else {
        const float4* fp = (const float4*)(feat + (size_t)pFa[0] * EDGE_INx + lg * 8);
        fa_n = fp[0]; fc_n = fp[1];
    }

    #pragma unroll
    for (int tc = 0; tc < 4; ++tc) {
        int b16 = tc * 16;

        bf16x8 fB;
        if constexpr (BF16F) {
            if (tc < 2)
                fbv[tc + 2] = *(const bf16x8*)(fbT + (size_t)pFa[tc + 2] * 32 + lg * 8);
            fB = fbv[tc];
        } else {
            float4 fa = fa_n, fc = fc_n;
            if (tc < 3) {
                const float4* fp = (const float4*)(feat + (size_t)pFa[tc + 1] * EDGE_INx + lg * 8);
                fa_n = fp[0]; fc_n = fp[1];
            }
            fB = mk8(cvtpk(fa.x, fa.y), cvtpk(fa.z, fa.w),
                     cvtpk(fc.x, fc.y), cvtpk(fc.z, fc.w));
        }

        // ---- per-tile meta via shfl; issue hx gathers early ----
        int sidv[4];
        #pragma unroll
        for (int r = 0; r < 4; ++r)
            sidv[r] = __shfl(s_own, b16 + lg * 4 + r, 64);
        int rF = __shfl(r_own, b16, 64);
        int rL = __shfl(r_own, b16 + 15, 64);

        float hv[4][4];   // [tn][r] — issued here, consumed after GEMM2
        if (!partial) {
            #pragma unroll
            for (int r = 0; r < 4; ++r) {
                const float* hp = hx + sidv[r] * TPSx + cr;
                #pragma unroll
                for (int tn = 0; tn < 4; ++tn)
                    hv[tn][r] = hp[tn * 16];
            }
        } else {
            #pragma unroll
            for (int r = 0; r < 4; ++r) {
                bool aE = (ebase + b16 + lg * 4 + r) < nE;
                const float* hp = hx + sidv[r] * TPSx + cr;
                #pragma unroll
                for (int tn = 0; tn < 4; ++tn)
                    hv[tn][r] = aE ? hp[tn * 16] : 0.f;
            }
        }

        // ---- GEMM1: e^T tiles ----
        f32x4 d1[4];
        #pragma unroll
        for (int tr = 0; tr < 4; ++tr)
            d1[tr] = __builtin_amdgcn_mfma_f32_16x16x32_bf16(uf[tr], fB, zero4, 0, 0, 0);

        // ---- silu + pack + per-wave LDS transpose write ----
        #pragma unroll
        for (int tr = 0; tr < 4; ++tr) {
            float v0 = silu_f(d1[tr][0] + ubv[tr].x);
            float v1 = silu_f(d1[tr][1] + ubv[tr].y);
            float v2 = silu_f(d1[tr][2] + ubv[tr].z);
            float v3 = silu_f(d1[tr][3] + ubv[tr].w);
            u32x2 pk; pk[0] = cvtpk(v0, v1); pk[1] = cvtpk(v2, v3);
            *(u32x2*)(ebuf + cr * 144 + tr * 32 + lg * 8) = pk;
        }

        // ---- read A-frags of e (same-wave DS ordering: no barrier) ----
        bf16x8 ebf0 = *(const bf16x8*)(ebuf + cr * 144 + 0 * 64 + lg * 16);
        bf16x8 ebf1 = *(const bf16x8*)(ebuf + cr * 144 + 1 * 64 + lg * 16);

        // ---- GEMM2: we tiles ----
        f32x4 d2[4];
        #pragma unroll
        for (int tn = 0; tn < 4; ++tn) {
            f32x4 acc = __builtin_amdgcn_mfma_f32_16x16x32_bf16(ebf0, wf[tn][0], zero4, 0, 0, 0);
            d2[tn] = __builtin_amdgcn_mfma_f32_16x16x32_bf16(ebf1, wf[tn][1], acc, 0, 0, 0);
        }

        // ---- message values ----
        float m[4][4];   // [tn][r]
        #pragma unroll
        for (int tn = 0; tn < 4; ++tn)
            #pragma unroll
            for (int r = 0; r < 4; ++r)
                m[tn][r] = silu_f(d2[tn][r] + wbv[tn]) * hv[tn][r];

        // ---- segment handling: accumulate in regs, flush on receiver change ----
        if (rF == rL) {
            if (rF != curR) { flush(); curR = rF; }
            #pragma unroll
            for (int tn = 0; tn < 4; ++tn)
                accv[tn] += (m[tn][0] + m[tn][1]) + (m[tn][2] + m[tn][3]);
        } else {
            flush();
            curR = -1;
            int ridv[4];
            #pragma unroll
            for (int r = 0; r < 4; ++r)
                ridv[r] = __shfl(r_own, b16 + lg * 4 + r, 64);
            float a0 = m[0][0], a1 = m[1][0], a2 = m[2][0], a3 = m[3][0];
            int segR = ridv[0];
            #pragma unroll
            for (int r = 1; r < 4; ++r) {
                if (ridv[r] != segR) {
                    atomicAdd(&zt[segR * 64 +  0 + cr], a0);
                    atomicAdd(&zt[segR * 64 + 16 + cr], a1);
                    atomicAdd(&zt[segR * 64 + 32 + cr], a2);
                    atomicAdd(&zt[segR * 64 + 48 + cr], a3);
                    a0 = m[0][r]; a1 = m[1][r]; a2 = m[2][r]; a3 = m[3][r];
                    segR = ridv[r];
                } else {
                    a0 += m[0][r]; a1 += m[1][r]; a2 += m[2][r]; a3 += m[3][r];
                }
            }
            atomicAdd(&zt[segR * 64 +  0 + cr], a0);
            atomicAdd(&zt[segR * 64 + 16 + cr], a1);
            atomicAdd(&zt[segR * 64 + 32 + cr], a2);
            atomicAdd(&zt[segR * 64 + 48 + cr], a3);
        }
    }
    flush();
}

// ---------------- final kernel: g-subnets + residual ----------------
__global__ __launch_bounds__(128)
void final_kernel(const float* __restrict__ elec, const float* __restrict__ z,
                  const float* __restrict__ gWres, const float* __restrict__ gbres,
                  const float* __restrict__ gWz, const float* __restrict__ gbz,
                  float* __restrict__ out)
{
    __shared__ float xe[4 * 128];
    __shared__ float xz[3 * 4 * 64];
    int b = blockIdx.x;
    int tid = threadIdx.x;
    int row0 = b * 4;
    for (int i = tid; i < 4 * 128; i += 128)
        xe[i] = elec[row0 * 128 + i];
    for (int i = tid; i < 3 * 4 * 64; i += 128) {
        int t = i >> 8; int rr = (i >> 6) & 3; int k = i & 63;
        xz[i] = z[t * N_ELx * 64 + (row0 + rr) * 64 + k];
    }
    __syncthreads();

    int col = tid;
    float accr[4] = {0.f, 0.f, 0.f, 0.f};
    for (int k = 0; k < 128; ++k) {
        float wv = gWres[k * 128 + col];
        #pragma unroll
        for (int r = 0; r < 4; ++r) accr[r] += xe[r * 128 + k] * wv;
    }
    float o[4];
    float br = gbres[col];
    #pragma unroll
    for (int r = 0; r < 4; ++r) o[r] = silu_f(accr[r] + br) + xe[r * 128 + col];

    for (int t = 0; t < 3; ++t) {
        float accz[4] = {0.f, 0.f, 0.f, 0.f};
        for (int k = 0; k < 64; ++k) {
            float wv = gWz[(t * 64 + k) * 128 + col];
            #pragma unroll
            for (int r = 0; r < 4; ++r) accz[r] += xz[t * 256 + r * 64 + k] * wv;
        }
        float bz = gbz[t * 128 + col];
        #pragma unroll
        for (int r = 0; r < 4; ++r) o[r] += silu_f(accz[r] + bz);
    }
    #pragma unroll
    for (int r = 0; r < 4; ++r) out[(row0 + r) * 128 + col] = o[r];
}

extern "C" void kernel_launch(void* const* d_in, const int* in_sizes, int n_in,
                              void* d_out, int out_size, void* d_ws, size_t ws_size,
                              hipStream_t stream)
{
    const float* elec   = (const float*)d_in[0];
    const float* nuclei = (const float*)d_in[1];
    const float* feat0  = (const float*)d_in[2];
    const float* feat1  = (const float*)d_in[3];
    const float* feat2  = (const float*)d_in[4];
    const int*   s0     = (const int*)d_in[5];
    const int*   r0     = (const int*)d_in[6];
    const int*   s1     = (const int*)d_in[7];
    const int*   r1     = (const int*)d_in[8];
    const int*   s2     = (const int*)d_in[9];
    const int*   r2     = (const int*)d_in[10];
    const float* u_W    = (const float*)d_in[11];
    const float* u_b    = (const float*)d_in[12];
    const float* w_W    = (const float*)d_in[13];
    const float* w_b    = (const float*)d_in[14];
    const float* hWee   = (const float*)d_in[15];
    const float* hbee   = (const float*)d_in[16];
    const float* hWne   = (const float*)d_in[17];
    const float* hbne   = (const float*)d_in[18];
    const float* gWres  = (const float*)d_in[19];
    const float* gbres  = (const float*)d_in[20];
    const float* gWz    = (const float*)d_in[21];
    const float* gbz    = (const float*)d_in[22];
    float* out = (float*)d_out;

    char* ws = (char*)d_ws;
    float* hx0      = (float*)(ws + 0);           // 196608
    float* hx1      = (float*)(ws + 196608);      // 196608
    float* hxn      = (float*)(ws + 393216);      // 8192
    float* z        = (float*)(ws + 401408);      // 589824
    short* ufragT   = (short*)(ws + 991232);      // 12288
    short* wWfrag   = (short*)(ws + 1003520);     // 24576
    int*   binTotal = (int*)(ws + 1028096);       // 9216
    int*   perm     = (int*)(ws + 1046528);       // 2454528
    int*   blockHist= (int*)(ws + 3501056);       // 884736  (end: 4385792)
    short* featbf   = (short*)(ws + 4385792);     // totalE*64 bytes (if it fits)

    int n0 = in_sizes[2] / EDGE_INx;
    int n1 = in_sizes[3] / EDGE_INx;
    int n2 = in_sizes[4] / EDGE_INx;
    int nb0 = (n0 + EPB - 1) / EPB;
    int nb1 = (n1 + EPB - 1) / EPB;
    int nb2 = (n2 + EPB - 1) / EPB;
    long long totalE = (long long)n0 + n1 + n2;
    bool useBf = (ws_size >= 4385792ull + (unsigned long long)totalE * 64ull)
                 && (n0 % 128 == 0) && (n1 % 128 == 0) && (n2 % 128 == 0);
    int nc0 = useBf ? n0 / 128 : 0;     // conversion blocks (1024 float4s each)
    int nc1 = useBf ? n1 / 128 : 0;
    int nc2 = useBf ? n2 / 128 : 0;

    setup_kernel<<<SETUP_FIXED + nc0 + nc1 + nc2, 256, 0, stream>>>(
        elec, nuclei, u_W, w_W, hWee, hbee, hWne, hbne,
        hx0, hx1, hxn, ufragT, wWfrag,
        r0, r1, r2, feat0, feat1, feat2, featbf,
        n0, n1, n2, nc0, nc1, blockHist, z);
    binscan_kernel<<<NBINS / 4, 256, 0, stream>>>(blockHist, binTotal);
    scatter2_kernel<<<NB_SORT, 256, 0, stream>>>(r0, r1, r2, n0, n1, n2,
                                                 blockHist, binTotal, perm);
    if (useBf) {
        edge_kernel<true><<<nb0 + nb1 + nb2, 256, 0, stream>>>(
            feat0, feat1, feat2, featbf, s0, s1, s2, r0, r1, r2,
            u_b, w_b, hx0, hx1, hxn, ufragT, wWfrag, perm, z,
            n0, n1, n2, nb0, nb1);
    } else {
        edge_kernel<false><<<nb0 + nb1 + nb2, 256, 0, stream>>>(
            feat0, feat1, feat2, featbf, s0, s1, s2, r0, r1, r2,
            u_b, w_b, hx0, hx1, hxn, ufragT, wWfrag, perm, z,
            n0, n1, n2, nb0, nb1);
    }
    final_kernel<<<192, 128, 0, stream>>>(elec, z, gWres, gbres, gWz, gbz, out);
}

// Round 13
// 94.514 us; speedup vs baseline: 1.2587x; 1.1063x over previous
//
#include <hip/hip_runtime.h>
#include <hip/hip_bf16.h>
#include <stdint.h>

#define N_ELx 768
#define EMBx 128
#define TPSx 64
#define EDGE_INx 32
#define EPB 256            // edges per block (4 waves x 64)
#define NBINS 2304         // 3 types * 768 receivers
#define NB_SORT 256
#define SETUP_FIXED 270    // 14 prep + 256 hist blocks

typedef __attribute__((ext_vector_type(8))) short bf16x8;
typedef __attribute__((ext_vector_type(4))) float f32x4;
typedef __attribute__((ext_vector_type(4))) uint32_t u32x4;
typedef __attribute__((ext_vector_type(2))) uint32_t u32x2;

__device__ __forceinline__ short f2bf(float f) {
    union { float f; uint32_t u; } v; v.f = f;
    uint32_t u = v.u;
    uint32_t r = (u + 0x7FFFu + ((u >> 16) & 1u)) >> 16;
    return (short)r;
}

// 1-instruction packed f32->bf16 pair (lo -> low16, hi -> high16), RNE
__device__ __forceinline__ uint32_t cvtpk(float lo, float hi) {
    uint32_t r;
    asm("v_cvt_pk_bf16_f32 %0, %1, %2" : "=v"(r) : "v"(lo), "v"(hi));
    return r;
}

__device__ __forceinline__ bf16x8 mk8(uint32_t a, uint32_t b, uint32_t c, uint32_t d) {
    union { u32x4 u; bf16x8 h; } x;
    x.u = (u32x4){a, b, c, d};
    return x.h;
}

// fast silu: avoids fp32 div sequence
__device__ __forceinline__ float silu_f(float x) {
    float e = __builtin_amdgcn_exp2f(-1.442695041f * x);
    return x * __builtin_amdgcn_rcpf(1.0f + e);
}

// ---- setup kernel: prep (blocks 0..13) + blockhist (14..269) ----------------
// hx tables are written TRANSPOSED within each row: hx[id][cr][tn] (cr=0..15,
// tn=0..3), so edge's epilogue reads one float4 per (id,cr) instead of 4
// stride-16 scalars.
__global__ __launch_bounds__(256)
void setup_kernel(const float* __restrict__ elec, const float* __restrict__ nuclei,
                  const float* __restrict__ uW, const float* __restrict__ wW,
                  const float* __restrict__ hWee, const float* __restrict__ hbee,
                  const float* __restrict__ hWne, const float* __restrict__ hbne,
                  float* __restrict__ hx0, float* __restrict__ hx1, float* __restrict__ hxn,
                  short* __restrict__ ufragT, short* __restrict__ wWfrag,
                  const int* __restrict__ r0, const int* __restrict__ r1,
                  const int* __restrict__ r2,
                  int n0, int n1, int n2, int* __restrict__ blockHist,
                  float* __restrict__ z)
{
    __shared__ __align__(16) char smem[32768];
    int b = blockIdx.x;
    int tid = threadIdx.x;
    if (b < 12) {
        short* lds_a = (short*)smem;   // [kk*4+kc][row][8]
        int t = b / 6, rb = b % 6;
        const float* W = hWee + t * (128 * 64);
        {
            int row = tid >> 1, half = tid & 1;
            const float4* src = (const float4*)(elec + (size_t)(rb * 128 + row) * 128 + half * 64);
            #pragma unroll
            for (int c = 0; c < 8; ++c) {
                float4 fa = src[c * 2 + 0], fb = src[c * 2 + 1];
                bf16x8 v;
                v[0] = f2bf(fa.x); v[1] = f2bf(fa.y); v[2] = f2bf(fa.z); v[3] = f2bf(fa.w);
                v[4] = f2bf(fb.x); v[5] = f2bf(fb.y); v[6] = f2bf(fb.z); v[7] = f2bf(fb.w);
                int kk = half * 2 + (c >> 2), kc = c & 3;
                *(bf16x8*)&lds_a[((kk * 4 + kc) * 128 + row) * 8] = v;
            }
        }
        __syncthreads();
        int lane = tid & 63, w = tid >> 6, kc = lane >> 4, cr = lane & 15;
        int col = w * 16 + cr;
        bf16x8 bfrag[4];
        #pragma unroll
        for (int kk = 0; kk < 4; ++kk) {
            bf16x8 v;
            #pragma unroll
            for (int j = 0; j < 8; ++j)
                v[j] = f2bf(W[(kk * 32 + kc * 8 + j) * 64 + col]);
            bfrag[kk] = v;
        }
        float bias = hbee[t * 64 + col];
        float* dst = (t == 0 ? hx0 : hx1);
        f32x4 zero4 = {0.f, 0.f, 0.f, 0.f};
        #pragma unroll
        for (int rt = 0; rt < 8; ++rt) {
            f32x4 acc = zero4;
            #pragma unroll
            for (int kk = 0; kk < 4; ++kk) {
                bf16x8 a = *(const bf16x8*)&lds_a[((kk * 4 + kc) * 128 + rt * 16 + cr) * 8];
                acc = __builtin_amdgcn_mfma_f32_16x16x32_bf16(a, bfrag[kk], acc, 0, 0, 0);
            }
            #pragma unroll
            for (int r = 0; r < 4; ++r) {
                int row = rb * 128 + rt * 16 + kc * 4 + r;
                dst[row * 64 + cr * 4 + w] = silu_f(acc[r] + bias);   // transposed
            }
        }
    } else if (b == 12) {
        // hxn: silu(nuclei @ hWne + hbne), 32x64 @ 64x64 (tiny, scalar)
        int lr = tid >> 6, col = tid & 63;
        for (int i = 0; i < 8; ++i) {
            int row = lr * 8 + i;
            float acc = 0.f;
            for (int k = 0; k < 64; ++k)
                acc += nuclei[row * 64 + k] * hWne[k * 64 + col];
            hxn[row * 64 + (col & 15) * 4 + (col >> 4)] = silu_f(acc + hbne[col]);
        }
    } else if (b == 13) {
        // ufragT: A-fragment of uW^T: A[ucol=tr*16+cr][k=featcol=lg*8+j]
        for (int idx = tid; idx < 3 * 4 * 64; idx += 256) {
            int lane = idx & 63, tr = (idx >> 6) & 3, ty = idx >> 8;
            int lg = lane >> 4, cr = lane & 15;
            for (int j = 0; j < 8; ++j)
                ufragT[idx * 8 + j] =
                    f2bf(uW[(ty * EDGE_INx + lg * 8 + j) * TPSx + tr * 16 + cr]);
        }
        // wWfrag: B-fragment of wW: B[k=ks*32+lg*8+j][col=tn*16+cr]
        for (int idx = tid; idx < 3 * 2 * 4 * 64; idx += 256) {
            int lane = idx & 63, ct = (idx >> 6) & 3, ks = (idx >> 8) & 1, ty = idx >> 9;
            for (int j = 0; j < 8; ++j) {
                int k = ks * 32 + (lane >> 4) * 8 + j, col = ct * 16 + (lane & 15);
                wWfrag[idx * 8 + j] = f2bf(wW[(ty * 64 + k) * 64 + col]);
            }
        }
    } else {
        // blockhist for sort + fold-in z zeroing
        int* h = (int*)smem;
        int bb = b - 14;                         // 0..255
        for (int i = bb * 256 + tid; i < 3 * N_ELx * TPSx; i += NB_SORT * 256)
            z[i] = 0.f;
        for (int i = tid; i < NBINS; i += 256) h[i] = 0;
        __syncthreads();
        int total = n0 + n1 + n2;
        int chunk = (total + NB_SORT - 1) / NB_SORT;
        int start = bb * chunk, end = min(start + chunk, total);
        for (int i = start + tid; i < end; i += 256) {
            int t, j;
            if (i < n0)            { t = 0; j = i; }
            else if (i < n0 + n1)  { t = 1; j = i - n0; }
            else                   { t = 2; j = i - n0 - n1; }
            int rv = (t == 0 ? r0 : (t == 1 ? r1 : r2))[j];
            atomicAdd(&h[t * 768 + rv], 1);
        }
        __syncthreads();
        for (int i = tid; i < NBINS; i += 256)
            blockHist[i * NB_SORT + bb] = h[i];
    }
}

// ---------------- sort: wave-per-bin parallel scan (256 entries) -------------
__global__ __launch_bounds__(256)
void binscan_kernel(int* __restrict__ blockHist, int* __restrict__ binTotal)
{
    int tid = threadIdx.x;
    int w = tid >> 6, lane = tid & 63;
    int bin = blockIdx.x * 4 + w;            // grid = NBINS/4 = 576
    int* p = blockHist + bin * NB_SORT;      // 256 entries
    int carry = 0;
    #pragma unroll
    for (int rnd = 0; rnd < NB_SORT / 64; ++rnd) {
        int a = p[rnd * 64 + lane];
        int a0 = a;
        #pragma unroll
        for (int d = 1; d < 64; d <<= 1) {
            int tv = __shfl_up(a, d, 64);
            if (lane >= d) a += tv;
        }
        int tot = __shfl(a, 63, 64);
        p[rnd * 64 + lane] = carry + a - a0;  // exclusive
        carry += tot;
    }
    if (lane == 0) binTotal[bin] = carry;
}

__global__ __launch_bounds__(256)
void scatter2_kernel(const int* __restrict__ r0, const int* __restrict__ r1,
                     const int* __restrict__ r2,
                     int n0, int n1, int n2,
                     const int* __restrict__ blockHist,
                     const int* __restrict__ binTotal,
                     int* __restrict__ perm)
{
    __shared__ int cursor[NBINS];
    __shared__ int part[256];
    int tid = threadIdx.x, b = blockIdx.x;   // grid = NB_SORT = 256
    int l[9]; int s = 0;
    #pragma unroll
    for (int j = 0; j < 9; ++j) { l[j] = binTotal[tid * 9 + j]; s += l[j]; }
    part[tid] = s;
    __syncthreads();
    for (int off = 1; off < 256; off <<= 1) {
        int v = (tid >= off) ? part[tid - off] : 0;
        __syncthreads();
        part[tid] += v;
        __syncthreads();
    }
    int run = (tid == 0) ? 0 : part[tid - 1];
    #pragma unroll
    for (int j = 0; j < 9; ++j) {
        int bin = tid * 9 + j;
        cursor[bin] = run + blockHist[bin * NB_SORT + b];
        run += l[j];
    }
    __syncthreads();
    int total = n0 + n1 + n2;
    int chunk = (total + NB_SORT - 1) / NB_SORT;
    int start = b * chunk, end = min(start + chunk, total);
    for (int i = start + tid; i < end; i += 256) {
        int t, j;
        if (i < n0)            { t = 0; j = i; }
        else if (i < n0 + n1)  { t = 1; j = i - n0; }
        else                   { t = 2; j = i - n0 - n1; }
        int rv = (t == 0 ? r0 : (t == 1 ? r1 : r2))[j];
        int pos = atomicAdd(&cursor[t * 768 + rv], 1);
        perm[pos] = j;
    }
}

// ---------------- edge kernel: 64 edges/wave, float4 hx, LDS transpose -------
__global__ __launch_bounds__(256)
void edge_kernel(const float* __restrict__ feat0, const float* __restrict__ feat1,
                 const float* __restrict__ feat2,
                 const int* __restrict__ s0, const int* __restrict__ s1, const int* __restrict__ s2,
                 const int* __restrict__ r0, const int* __restrict__ r1, const int* __restrict__ r2,
                 const float* __restrict__ u_b, const float* __restrict__ w_b,
                 const float* __restrict__ hx0, const float* __restrict__ hx1,
                 const float* __restrict__ hxn,
                 const short* __restrict__ ufragT, const short* __restrict__ wWfrag,
                 const int* __restrict__ perm,
                 float* __restrict__ z,
                 int n0, int n1, int n2, int nb0, int nb1)
{
    __shared__ __align__(16) char ebuf_all[4][16 * 144];   // 2304B per wave

    int b = blockIdx.x;
    int t; const float* feat; const int* sn; const int* rc; const float* hx; int nE;
    if (b < nb0)            { t = 0; feat = feat0; sn = s0; rc = r0; hx = hx0; nE = n0; }
    else if (b < nb0 + nb1) { t = 1; b -= nb0; feat = feat1; sn = s1; rc = r1; hx = hx1; nE = n1; }
    else                    { t = 2; b -= nb0 + nb1; feat = feat2; sn = s2; rc = r2; hx = hxn; nE = n2; }

    int tid = threadIdx.x;
    int w = tid >> 6, lane = tid & 63, lg = lane >> 4, cr = lane & 15;
    int ebase = b * EPB + w * 64;
    if (ebase >= nE) return;                    // fully-empty wave (no barriers used)
    bool partial = (ebase + 64 > nE);           // never true: all counts divide 256
    char* ebuf = ebuf_all[w];
    int t_off = (t == 0) ? 0 : (t == 1 ? n0 : n0 + n1);
    float* zt = z + t * (N_ELx * TPSx);

    // weight fragments + biases (L2-hot broadcast loads)
    bf16x8 uf[4];
    #pragma unroll
    for (int tr = 0; tr < 4; ++tr)
        uf[tr] = *(const bf16x8*)(ufragT + ((t * 4 + tr) * 64 + lane) * 8);
    bf16x8 wf[4][2];
    #pragma unroll
    for (int tn = 0; tn < 4; ++tn)
        #pragma unroll
        for (int ks = 0; ks < 2; ++ks)
            wf[tn][ks] = *(const bf16x8*)(wWfrag + (((t * 2 + ks) * 4 + tn) * 64 + lane) * 8);
    float4 ubv[4];
    #pragma unroll
    for (int tr = 0; tr < 4; ++tr)
        ubv[tr] = *(const float4*)(u_b + t * 64 + tr * 16 + lg * 4);
    float wbv[4];
    #pragma unroll
    for (int tn = 0; tn < 4; ++tn)
        wbv[tn] = w_b[t * 64 + tn * 16 + cr];

    // own-edge meta: lane owns edge ebase + lane
    int e_own = ebase + lane;
    int pe_own = perm[t_off + min(e_own, nE - 1)];
    int s_own = sn[pe_own];
    int r_own = rc[pe_own];

    f32x4 zero4 = {0.f, 0.f, 0.f, 0.f};

    // deferred segment accumulator
    float accv[4] = {0.f, 0.f, 0.f, 0.f};
    int curR = -1;
    auto flush = [&]() {
        if (curR >= 0) {
            #pragma unroll
            for (int tn = 0; tn < 4; ++tn) {
                float v = accv[tn];
                v += __shfl_xor(v, 16, 64);
                v += __shfl_xor(v, 32, 64);
                if (lg == 0) atomicAdd(&zt[curR * 64 + tn * 16 + cr], v);
                accv[tn] = 0.f;
            }
        }
    };

    // ---- feat row indices for all 4 tiles; prefetch tile 0 ----
    int pFa[4];
    #pragma unroll
    for (int tc = 0; tc < 4; ++tc)
        pFa[tc] = __shfl(pe_own, tc * 16 + cr, 64);
    float4 fa_n, fc_n;
    {
        const float4* fp = (const float4*)(feat + (size_t)pFa[0] * EDGE_INx + lg * 8);
        fa_n = fp[0]; fc_n = fp[1];
    }

    #pragma unroll
    for (int tc = 0; tc < 4; ++tc) {
        int b16 = tc * 16;
        float4 fa = fa_n, fc = fc_n;

        // ---- prefetch feat for tile tc+1 ----
        if (tc < 3) {
            const float4* fp = (const float4*)(feat + (size_t)pFa[tc + 1] * EDGE_INx + lg * 8);
            fa_n = fp[0]; fc_n = fp[1];
        }

        // ---- per-tile meta via shfl; issue hx gathers (float4) early ----
        int sidv[4];
        #pragma unroll
        for (int r = 0; r < 4; ++r)
            sidv[r] = __shfl(s_own, b16 + lg * 4 + r, 64);
        int rF = __shfl(r_own, b16, 64);
        int rL = __shfl(r_own, b16 + 15, 64);

        float4 hv4[4];   // [r] -> (tn=0..3), via transposed hx layout
        if (!partial) {
            #pragma unroll
            for (int r = 0; r < 4; ++r)
                hv4[r] = ((const float4*)(hx + sidv[r] * TPSx))[cr];
        } else {
            #pragma unroll
            for (int r = 0; r < 4; ++r) {
                bool aE = (ebase + b16 + lg * 4 + r) < nE;
                hv4[r] = aE ? ((const float4*)(hx + sidv[r] * TPSx))[cr]
                            : make_float4(0.f, 0.f, 0.f, 0.f);
            }
        }

        // ---- feat B-frag ----
        bf16x8 fB = mk8(cvtpk(fa.x, fa.y), cvtpk(fa.z, fa.w),
                        cvtpk(fc.x, fc.y), cvtpk(fc.z, fc.w));

        // ---- GEMM1: e^T tiles ----
        f32x4 d1[4];
        #pragma unroll
        for (int tr = 0; tr < 4; ++tr)
            d1[tr] = __builtin_amdgcn_mfma_f32_16x16x32_bf16(uf[tr], fB, zero4, 0, 0, 0);

        // ---- silu + pack + per-wave LDS transpose write ----
        #pragma unroll
        for (int tr = 0; tr < 4; ++tr) {
            float v0 = silu_f(d1[tr][0] + ubv[tr].x);
            float v1 = silu_f(d1[tr][1] + ubv[tr].y);
            float v2 = silu_f(d1[tr][2] + ubv[tr].z);
            float v3 = silu_f(d1[tr][3] + ubv[tr].w);
            u32x2 pk; pk[0] = cvtpk(v0, v1); pk[1] = cvtpk(v2, v3);
            *(u32x2*)(ebuf + cr * 144 + tr * 32 + lg * 8) = pk;
        }

        // ---- read A-frags of e (same-wave DS ordering: no barrier) ----
        bf16x8 ebf0 = *(const bf16x8*)(ebuf + cr * 144 + 0 * 64 + lg * 16);
        bf16x8 ebf1 = *(const bf16x8*)(ebuf + cr * 144 + 1 * 64 + lg * 16);

        // ---- GEMM2: we tiles ----
        f32x4 d2[4];
        #pragma unroll
        for (int tn = 0; tn < 4; ++tn) {
            f32x4 acc = __builtin_amdgcn_mfma_f32_16x16x32_bf16(ebf0, wf[tn][0], zero4, 0, 0, 0);
            d2[tn] = __builtin_amdgcn_mfma_f32_16x16x32_bf16(ebf1, wf[tn][1], acc, 0, 0, 0);
        }

        // ---- message values (hv4[r][tn] from transposed hx) ----
        float m[4][4];   // [tn][r]
        #pragma unroll
        for (int r = 0; r < 4; ++r) {
            m[0][r] = silu_f(d2[0][r] + wbv[0]) * hv4[r].x;
            m[1][r] = silu_f(d2[1][r] + wbv[1]) * hv4[r].y;
            m[2][r] = silu_f(d2[2][r] + wbv[2]) * hv4[r].z;
            m[3][r] = silu_f(d2[3][r] + wbv[3]) * hv4[r].w;
        }

        // ---- segment handling: accumulate in regs, flush on receiver change ----
        if (rF == rL) {
            if (rF != curR) { flush(); curR = rF; }
            #pragma unroll
            for (int tn = 0; tn < 4; ++tn)
                accv[tn] += (m[tn][0] + m[tn][1]) + (m[tn][2] + m[tn][3]);
        } else {
            flush();
            curR = -1;
            int ridv[4];
            #pragma unroll
            for (int r = 0; r < 4; ++r)
                ridv[r] = __shfl(r_own, b16 + lg * 4 + r, 64);
            float a0 = m[0][0], a1 = m[1][0], a2 = m[2][0], a3 = m[3][0];
            int segR = ridv[0];
            #pragma unroll
            for (int r = 1; r < 4; ++r) {
                if (ridv[r] != segR) {
                    atomicAdd(&zt[segR * 64 +  0 + cr], a0);
                    atomicAdd(&zt[segR * 64 + 16 + cr], a1);
                    atomicAdd(&zt[segR * 64 + 32 + cr], a2);
                    atomicAdd(&zt[segR * 64 + 48 + cr], a3);
                    a0 = m[0][r]; a1 = m[1][r]; a2 = m[2][r]; a3 = m[3][r];
                    segR = ridv[r];
                } else {
                    a0 += m[0][r]; a1 += m[1][r]; a2 += m[2][r]; a3 += m[3][r];
                }
            }
            atomicAdd(&zt[segR * 64 +  0 + cr], a0);
            atomicAdd(&zt[segR * 64 + 16 + cr], a1);
            atomicAdd(&zt[segR * 64 + 32 + cr], a2);
            atomicAdd(&zt[segR * 64 + 48 + cr], a3);
        }
    }
    flush();
}

// ---------------- final kernel: g-subnets + residual ----------------
__global__ __launch_bounds__(128)
void final_kernel(const float* __restrict__ elec, const float* __restrict__ z,
                  const float* __restrict__ gWres, const float* __restrict__ gbres,
                  const float* __restrict__ gWz, const float* __restrict__ gbz,
                  float* __restrict__ out)
{
    __shared__ float xe[4 * 128];
    __shared__ float xz[3 * 4 * 64];
    int b = blockIdx.x;
    int tid = threadIdx.x;
    int row0 = b * 4;
    for (int i = tid; i < 4 * 128; i += 128)
        xe[i] = elec[row0 * 128 + i];
    for (int i = tid; i < 3 * 4 * 64; i += 128) {
        int t = i >> 8; int rr = (i >> 6) & 3; int k = i & 63;
        xz[i] = z[t * N_ELx * 64 + (row0 + rr) * 64 + k];
    }
    __syncthreads();

    int col = tid;
    float accr[4] = {0.f, 0.f, 0.f, 0.f};
    for (int k = 0; k < 128; ++k) {
        float wv = gWres[k * 128 + col];
        #pragma unroll
        for (int r = 0; r < 4; ++r) accr[r] += xe[r * 128 + k] * wv;
    }
    float o[4];
    float br = gbres[col];
    #pragma unroll
    for (int r = 0; r < 4; ++r) o[r] = silu_f(accr[r] + br) + xe[r * 128 + col];

    for (int t = 0; t < 3; ++t) {
        float accz[4] = {0.f, 0.f, 0.f, 0.f};
        for (int k = 0; k < 64; ++k) {
            float wv = gWz[(t * 64 + k) * 128 + col];
            #pragma unroll
            for (int r = 0; r < 4; ++r) accz[r] += xz[t * 256 + r * 64 + k] * wv;
        }
        float bz = gbz[t * 128 + col];
        #pragma unroll
        for (int r = 0; r < 4; ++r) o[r] += silu_f(accz[r] + bz);
    }
    #pragma unroll
    for (int r = 0; r < 4; ++r) out[(row0 + r) * 128 + col] = o[r];
}

extern "C" void kernel_launch(void* const* d_in, const int* in_sizes, int n_in,
                              void* d_out, int out_size, void* d_ws, size_t ws_size,
                              hipStream_t stream)
{
    const float* elec   = (const float*)d_in[0];
    const float* nuclei = (const float*)d_in[1];
    const float* feat0  = (const float*)d_in[2];
    const float* feat1  = (const float*)d_in[3];
    const float* feat2  = (const float*)d_in[4];
    const int*   s0     = (const int*)d_in[5];
    const int*   r0     = (const int*)d_in[6];
    const int*   s1     = (const int*)d_in[7];
    const int*   r1     = (const int*)d_in[8];
    const int*   s2     = (const int*)d_in[9];
    const int*   r2     = (const int*)d_in[10];
    const float* u_W    = (const float*)d_in[11];
    const float* u_b    = (const float*)d_in[12];
    const float* w_W    = (const float*)d_in[13];
    const float* w_b    = (const float*)d_in[14];
    const float* hWee   = (const float*)d_in[15];
    const float* hbee   = (const float*)d_in[16];
    const float* hWne   = (const float*)d_in[17];
    const float* hbne   = (const float*)d_in[18];
    const float* gWres  = (const float*)d_in[19];
    const float* gbres  = (const float*)d_in[20];
    const float* gWz    = (const float*)d_in[21];
    const float* gbz    = (const float*)d_in[22];
    float* out = (float*)d_out;

    char* ws = (char*)d_ws;
    float* hx0      = (float*)(ws + 0);           // 196608
    float* hx1      = (float*)(ws + 196608);      // 196608
    float* hxn      = (float*)(ws + 393216);      // 8192
    float* z        = (float*)(ws + 401408);      // 589824
    short* ufragT   = (short*)(ws + 991232);      // 12288
    short* wWfrag   = (short*)(ws + 1003520);     // 24576
    int*   binTotal = (int*)(ws + 1028096);       // 9216
    int*   perm     = (int*)(ws + 1046528);       // 2454528 (end 3501056)
    int*   blockHist= (int*)(ws + 3501056);       // 2359296 (end 5860352)

    int n0 = in_sizes[2] / EDGE_INx;
    int n1 = in_sizes[3] / EDGE_INx;
    int n2 = in_sizes[4] / EDGE_INx;
    int nb0 = (n0 + EPB - 1) / EPB;
    int nb1 = (n1 + EPB - 1) / EPB;
    int nb2 = (n2 + EPB - 1) / EPB;

    setup_kernel<<<SETUP_FIXED, 256, 0, stream>>>(
        elec, nuclei, u_W, w_W, hWee, hbee, hWne, hbne,
        hx0, hx1, hxn, ufragT, wWfrag,
        r0, r1, r2, n0, n1, n2, blockHist, z);
    binscan_kernel<<<NBINS / 4, 256, 0, stream>>>(blockHist, binTotal);
    scatter2_kernel<<<NB_SORT, 256, 0, stream>>>(r0, r1, r2, n0, n1, n2,
                                                 blockHist, binTotal, perm);
    edge_kernel<<<nb0 + nb1 + nb2, 256, 0, stream>>>(
        feat0, feat1, feat2, s0, s1, s2, r0, r1, r2,
        u_b, w_b, hx0, hx1, hxn, ufragT, wWfrag, perm, z,
        n0, n1, n2, nb0, nb1);
    final_kernel<<<192, 128, 0, stream>>>(elec, z, gWres, gbres, gWz, gbz, out);
}

// Round 14
// 92.671 us; speedup vs baseline: 1.2837x; 1.0199x over previous
//
#include <hip/hip_runtime.h>
#include <hip/hip_bf16.h>
#include <stdint.h>

#define N_ELx 768
#define EMBx 128
#define TPSx 64
#define EDGE_INx 32
#define EPB 256            // edges per block (4 waves x 64)
#define NBINS 2304         // 3 types * 768 receivers
#define NB_SORT 96
#define SETUP_FIXED 110    // 14 prep + 96 hist blocks

typedef __attribute__((ext_vector_type(8))) short bf16x8;
typedef __attribute__((ext_vector_type(4))) float f32x4;
typedef __attribute__((ext_vector_type(4))) uint32_t u32x4;
typedef __attribute__((ext_vector_type(2))) uint32_t u32x2;

__device__ __forceinline__ short f2bf(float f) {
    union { float f; uint32_t u; } v; v.f = f;
    uint32_t u = v.u;
    uint32_t r = (u + 0x7FFFu + ((u >> 16) & 1u)) >> 16;
    return (short)r;
}

// 1-instruction packed f32->bf16 pair (lo -> low16, hi -> high16), RNE
__device__ __forceinline__ uint32_t cvtpk(float lo, float hi) {
    uint32_t r;
    asm("v_cvt_pk_bf16_f32 %0, %1, %2" : "=v"(r) : "v"(lo), "v"(hi));
    return r;
}

__device__ __forceinline__ bf16x8 mk8(uint32_t a, uint32_t b, uint32_t c, uint32_t d) {
    union { u32x4 u; bf16x8 h; } x;
    x.u = (u32x4){a, b, c, d};
    return x.h;
}

// fast silu: avoids fp32 div sequence
__device__ __forceinline__ float silu_f(float x) {
    float e = __builtin_amdgcn_exp2f(-1.442695041f * x);
    return x * __builtin_amdgcn_rcpf(1.0f + e);
}

// ---- setup kernel: prep (blocks 0..13) + blockhist (14..109) ----------------
// hx tables written TRANSPOSED within each row: hx[id][cr][tn] so edge's
// epilogue reads one float4 per (id,cr).
__global__ __launch_bounds__(256)
void setup_kernel(const float* __restrict__ elec, const float* __restrict__ nuclei,
                  const float* __restrict__ uW, const float* __restrict__ wW,
                  const float* __restrict__ hWee, const float* __restrict__ hbee,
                  const float* __restrict__ hWne, const float* __restrict__ hbne,
                  float* __restrict__ hx0, float* __restrict__ hx1, float* __restrict__ hxn,
                  short* __restrict__ ufragT, short* __restrict__ wWfrag,
                  const int* __restrict__ r0, const int* __restrict__ r1,
                  const int* __restrict__ r2,
                  int n0, int n1, int n2, int* __restrict__ blockHist,
                  float* __restrict__ z)
{
    __shared__ __align__(16) char smem[32768];
    int b = blockIdx.x;
    int tid = threadIdx.x;
    if (b < 12) {
        short* lds_a = (short*)smem;   // [kk*4+kc][row][8]
        int t = b / 6, rb = b % 6;
        const float* W = hWee + t * (128 * 64);
        {
            int row = tid >> 1, half = tid & 1;
            const float4* src = (const float4*)(elec + (size_t)(rb * 128 + row) * 128 + half * 64);
            #pragma unroll
            for (int c = 0; c < 8; ++c) {
                float4 fa = src[c * 2 + 0], fb = src[c * 2 + 1];
                bf16x8 v;
                v[0] = f2bf(fa.x); v[1] = f2bf(fa.y); v[2] = f2bf(fa.z); v[3] = f2bf(fa.w);
                v[4] = f2bf(fb.x); v[5] = f2bf(fb.y); v[6] = f2bf(fb.z); v[7] = f2bf(fb.w);
                int kk = half * 2 + (c >> 2), kc = c & 3;
                *(bf16x8*)&lds_a[((kk * 4 + kc) * 128 + row) * 8] = v;
            }
        }
        __syncthreads();
        int lane = tid & 63, w = tid >> 6, kc = lane >> 4, cr = lane & 15;
        int col = w * 16 + cr;
        bf16x8 bfrag[4];
        #pragma unroll
        for (int kk = 0; kk < 4; ++kk) {
            bf16x8 v;
            #pragma unroll
            for (int j = 0; j < 8; ++j)
                v[j] = f2bf(W[(kk * 32 + kc * 8 + j) * 64 + col]);
            bfrag[kk] = v;
        }
        float bias = hbee[t * 64 + col];
        float* dst = (t == 0 ? hx0 : hx1);
        f32x4 zero4 = {0.f, 0.f, 0.f, 0.f};
        #pragma unroll
        for (int rt = 0; rt < 8; ++rt) {
            f32x4 acc = zero4;
            #pragma unroll
            for (int kk = 0; kk < 4; ++kk) {
                bf16x8 a = *(const bf16x8*)&lds_a[((kk * 4 + kc) * 128 + rt * 16 + cr) * 8];
                acc = __builtin_amdgcn_mfma_f32_16x16x32_bf16(a, bfrag[kk], acc, 0, 0, 0);
            }
            #pragma unroll
            for (int r = 0; r < 4; ++r) {
                int row = rb * 128 + rt * 16 + kc * 4 + r;
                dst[row * 64 + cr * 4 + w] = silu_f(acc[r] + bias);   // transposed
            }
        }
    } else if (b == 12) {
        // hxn: silu(nuclei @ hWne + hbne), transposed write
        int lr = tid >> 6, col = tid & 63;
        for (int i = 0; i < 8; ++i) {
            int row = lr * 8 + i;
            float acc = 0.f;
            for (int k = 0; k < 64; ++k)
                acc += nuclei[row * 64 + k] * hWne[k * 64 + col];
            hxn[row * 64 + (col & 15) * 4 + (col >> 4)] = silu_f(acc + hbne[col]);
        }
    } else if (b == 13) {
        // ufragT: A-fragment of uW^T: A[ucol=tr*16+cr][k=featcol=lg*8+j]
        for (int idx = tid; idx < 3 * 4 * 64; idx += 256) {
            int lane = idx & 63, tr = (idx >> 6) & 3, ty = idx >> 8;
            int lg = lane >> 4, cr = lane & 15;
            for (int j = 0; j < 8; ++j)
                ufragT[idx * 8 + j] =
                    f2bf(uW[(ty * EDGE_INx + lg * 8 + j) * TPSx + tr * 16 + cr]);
        }
        // wWfrag: B-fragment of wW: B[k=ks*32+lg*8+j][col=tn*16+cr]
        for (int idx = tid; idx < 3 * 2 * 4 * 64; idx += 256) {
            int lane = idx & 63, ct = (idx >> 6) & 3, ks = (idx >> 8) & 1, ty = idx >> 9;
            for (int j = 0; j < 8; ++j) {
                int k = ks * 32 + (lane >> 4) * 8 + j, col = ct * 16 + (lane & 15);
                wWfrag[idx * 8 + j] = f2bf(wW[(ty * 64 + k) * 64 + col]);
            }
        }
    } else {
        // blockhist for sort + fold-in z zeroing
        int* h = (int*)smem;
        int bb = b - 14;                         // 0..95
        for (int i = bb * 256 + tid; i < 3 * N_ELx * TPSx; i += NB_SORT * 256)
            z[i] = 0.f;
        for (int i = tid; i < NBINS; i += 256) h[i] = 0;
        __syncthreads();
        int total = n0 + n1 + n2;
        int chunk = (total + NB_SORT - 1) / NB_SORT;
        int start = bb * chunk, end = min(start + chunk, total);
        for (int i = start + tid; i < end; i += 256) {
            int t, j;
            if (i < n0)            { t = 0; j = i; }
            else if (i < n0 + n1)  { t = 1; j = i - n0; }
            else                   { t = 2; j = i - n0 - n1; }
            int rv = (t == 0 ? r0 : (t == 1 ? r1 : r2))[j];
            atomicAdd(&h[t * 768 + rv], 1);
        }
        __syncthreads();
        for (int i = tid; i < NBINS; i += 256)
            blockHist[i * NB_SORT + bb] = h[i];
    }
}

// ---------------- sort: wave-per-bin parallel scan (96 entries) --------------
__global__ __launch_bounds__(256)
void binscan_kernel(int* __restrict__ blockHist, int* __restrict__ binTotal)
{
    int tid = threadIdx.x;
    int w = tid >> 6, lane = tid & 63;
    int bin = blockIdx.x * 4 + w;            // grid = NBINS/4 = 576
    int* p = blockHist + bin * NB_SORT;      // 96 entries
    int a = p[lane];
    int bv = (lane < 32) ? p[64 + lane] : 0;
    int a0 = a, b0 = bv;
    #pragma unroll
    for (int d = 1; d < 64; d <<= 1) {
        int tv = __shfl_up(a, d, 64);
        if (lane >= d) a += tv;
    }
    int sumA = __shfl(a, 63, 64);
    #pragma unroll
    for (int d = 1; d < 32; d <<= 1) {
        int tv = __shfl_up(bv, d, 64);
        if (lane >= d) bv += tv;
    }
    p[lane] = a - a0;                        // exclusive
    if (lane < 32) p[64 + lane] = sumA + bv - b0;
    if (lane == 31) binTotal[bin] = sumA + bv;
}

__global__ __launch_bounds__(256)
void scatter2_kernel(const int* __restrict__ r0, const int* __restrict__ r1,
                     const int* __restrict__ r2,
                     int n0, int n1, int n2,
                     const int* __restrict__ blockHist,
                     const int* __restrict__ binTotal,
                     int* __restrict__ perm)
{
    __shared__ int cursor[NBINS];
    __shared__ int part[256];
    int tid = threadIdx.x, b = blockIdx.x;
    int l[9]; int s = 0;
    #pragma unroll
    for (int j = 0; j < 9; ++j) { l[j] = binTotal[tid * 9 + j]; s += l[j]; }
    part[tid] = s;
    __syncthreads();
    for (int off = 1; off < 256; off <<= 1) {
        int v = (tid >= off) ? part[tid - off] : 0;
        __syncthreads();
        part[tid] += v;
        __syncthreads();
    }
    int run = (tid == 0) ? 0 : part[tid - 1];
    #pragma unroll
    for (int j = 0; j < 9; ++j) {
        int bin = tid * 9 + j;
        cursor[bin] = run + blockHist[bin * NB_SORT + b];
        run += l[j];
    }
    __syncthreads();
    int total = n0 + n1 + n2;
    int chunk = (total + NB_SORT - 1) / NB_SORT;
    int start = b * chunk, end = min(start + chunk, total);
    for (int i = start + tid; i < end; i += 256) {
        int t, j;
        if (i < n0)            { t = 0; j = i; }
        else if (i < n0 + n1)  { t = 1; j = i - n0; }
        else                   { t = 2; j = i - n0 - n1; }
        int rv = (t == 0 ? r0 : (t == 1 ? r1 : r2))[j];
        int pos = atomicAdd(&cursor[t * 768 + rv], 1);
        perm[pos] = j;
    }
}

// ---- edge kernel: LDS weights (no launch-bounds force) + full feat prefetch --
__global__ __launch_bounds__(256)
void edge_kernel(const float* __restrict__ feat0, const float* __restrict__ feat1,
                 const float* __restrict__ feat2,
                 const int* __restrict__ s0, const int* __restrict__ s1, const int* __restrict__ s2,
                 const int* __restrict__ r0, const int* __restrict__ r1, const int* __restrict__ r2,
                 const float* __restrict__ u_b, const float* __restrict__ w_b,
                 const float* __restrict__ hx0, const float* __restrict__ hx1,
                 const float* __restrict__ hxn,
                 const short* __restrict__ ufragT, const short* __restrict__ wWfrag,
                 const int* __restrict__ perm,
                 float* __restrict__ z,
                 int n0, int n1, int n2, int nb0, int nb1)
{
    __shared__ __align__(16) short wt_lds[12 * 64 * 8];     // uf 4KB | wf 8KB
    __shared__ __align__(16) char ebuf_all[4][16 * 144];    // 2304B per wave

    int b = blockIdx.x;
    int t; const float* feat; const int* sn; const int* rc; const float* hx; int nE;
    if (b < nb0)            { t = 0; feat = feat0; sn = s0; rc = r0; hx = hx0; nE = n0; }
    else if (b < nb0 + nb1) { t = 1; b -= nb0; feat = feat1; sn = s1; rc = r1; hx = hx1; nE = n1; }
    else                    { t = 2; b -= nb0 + nb1; feat = feat2; sn = s2; rc = r2; hx = hxn; nE = n2; }

    int tid = threadIdx.x;
    int w = tid >> 6, lane = tid & 63, lg = lane >> 4, cr = lane & 15;
    int ebase = b * EPB + w * 64;

    // stage weight fragments (shared by the block's 4 waves), then barrier
    {
        const short* usrc = ufragT + t * (4 * 64 * 8);
        *(bf16x8*)&wt_lds[tid * 8] = *(const bf16x8*)&usrc[tid * 8];
        const short* wsrc = wWfrag + t * (2 * 4 * 64 * 8);
        *(bf16x8*)&wt_lds[(256 + tid) * 8] = *(const bf16x8*)&wsrc[tid * 8];
        *(bf16x8*)&wt_lds[(512 + tid) * 8] = *(const bf16x8*)&wsrc[(256 + tid) * 8];
    }
    __syncthreads();
    if (ebase >= nE) return;                    // no barriers after this point
    bool partial = (ebase + 64 > nE);           // never true: all counts divide 256
    char* ebuf = ebuf_all[w];
    int t_off = (t == 0) ? 0 : (t == 1 ? n0 : n0 + n1);
    float* zt = z + t * (N_ELx * TPSx);

    // biases in registers (20)
    float4 ubv[4];
    #pragma unroll
    for (int tr = 0; tr < 4; ++tr)
        ubv[tr] = *(const float4*)(u_b + t * 64 + tr * 16 + lg * 4);
    float wbv[4];
    #pragma unroll
    for (int tn = 0; tn < 4; ++tn)
        wbv[tn] = w_b[t * 64 + tn * 16 + cr];

    // own-edge meta: lane owns edge ebase + lane
    int e_own = ebase + lane;
    int pe_own = perm[t_off + min(e_own, nE - 1)];
    int s_own = sn[pe_own];
    int r_own = rc[pe_own];

    f32x4 zero4 = {0.f, 0.f, 0.f, 0.f};

    // deferred segment accumulator
    float accv[4] = {0.f, 0.f, 0.f, 0.f};
    int curR = -1;
    auto flush = [&]() {
        if (curR >= 0) {
            #pragma unroll
            for (int tn = 0; tn < 4; ++tn) {
                float v = accv[tn];
                v += __shfl_xor(v, 16, 64);
                v += __shfl_xor(v, 32, 64);
                if (lg == 0) atomicAdd(&zt[curR * 64 + tn * 16 + cr], v);
                accv[tn] = 0.f;
            }
        }
    };

    // ---- ALL 4 tiles' feat loads issued in the prologue (8 in flight) ----
    int pFa[4];
    #pragma unroll
    for (int tc = 0; tc < 4; ++tc)
        pFa[tc] = __shfl(pe_own, tc * 16 + cr, 64);
    float4 fav[4], fcv[4];
    #pragma unroll
    for (int tc = 0; tc < 4; ++tc) {
        const float4* fp = (const float4*)(feat + (size_t)pFa[tc] * EDGE_INx + lg * 8);
        fav[tc] = fp[0]; fcv[tc] = fp[1];
    }

    #pragma unroll
    for (int tc = 0; tc < 4; ++tc) {
        int b16 = tc * 16;

        // ---- per-tile meta via shfl; issue hx gathers (float4) early ----
        int sidv[4];
        #pragma unroll
        for (int r = 0; r < 4; ++r)
            sidv[r] = __shfl(s_own, b16 + lg * 4 + r, 64);
        int rF = __shfl(r_own, b16, 64);
        int rL = __shfl(r_own, b16 + 15, 64);

        float4 hv4[4];   // [r] -> (tn=0..3), via transposed hx layout
        if (!partial) {
            #pragma unroll
            for (int r = 0; r < 4; ++r)
                hv4[r] = ((const float4*)(hx + sidv[r] * TPSx))[cr];
        } else {
            #pragma unroll
            for (int r = 0; r < 4; ++r) {
                bool aE = (ebase + b16 + lg * 4 + r) < nE;
                hv4[r] = aE ? ((const float4*)(hx + sidv[r] * TPSx))[cr]
                            : make_float4(0.f, 0.f, 0.f, 0.f);
            }
        }

        // ---- feat B-frag from prefetched regs ----
        float4 fa = fav[tc], fc = fcv[tc];
        bf16x8 fB = mk8(cvtpk(fa.x, fa.y), cvtpk(fa.z, fa.w),
                        cvtpk(fc.x, fc.y), cvtpk(fc.z, fc.w));

        // ---- GEMM1: e^T tiles (uf read from LDS, lane-invariant addr) ----
        f32x4 d1[4];
        #pragma unroll
        for (int tr = 0; tr < 4; ++tr) {
            bf16x8 a = *(const bf16x8*)&wt_lds[(tr * 64 + lane) * 8];
            d1[tr] = __builtin_amdgcn_mfma_f32_16x16x32_bf16(a, fB, zero4, 0, 0, 0);
        }

        // ---- silu + pack + per-wave LDS transpose write ----
        #pragma unroll
        for (int tr = 0; tr < 4; ++tr) {
            float v0 = silu_f(d1[tr][0] + ubv[tr].x);
            float v1 = silu_f(d1[tr][1] + ubv[tr].y);
            float v2 = silu_f(d1[tr][2] + ubv[tr].z);
            float v3 = silu_f(d1[tr][3] + ubv[tr].w);
            u32x2 pk; pk[0] = cvtpk(v0, v1); pk[1] = cvtpk(v2, v3);
            *(u32x2*)(ebuf + cr * 144 + tr * 32 + lg * 8) = pk;
        }

        // ---- read A-frags of e (same-wave DS ordering: no barrier) ----
        bf16x8 ebf0 = *(const bf16x8*)(ebuf + cr * 144 + 0 * 64 + lg * 16);
        bf16x8 ebf1 = *(const bf16x8*)(ebuf + cr * 144 + 1 * 64 + lg * 16);

        // ---- GEMM2: we tiles (wf read from LDS) ----
        f32x4 d2[4];
        #pragma unroll
        for (int tn = 0; tn < 4; ++tn) {
            bf16x8 w0 = *(const bf16x8*)&wt_lds[(256 + tn * 64 + lane) * 8];
            bf16x8 w1 = *(const bf16x8*)&wt_lds[(256 + (4 + tn) * 64 + lane) * 8];
            f32x4 acc = __builtin_amdgcn_mfma_f32_16x16x32_bf16(ebf0, w0, zero4, 0, 0, 0);
            d2[tn] = __builtin_amdgcn_mfma_f32_16x16x32_bf16(ebf1, w1, acc, 0, 0, 0);
        }

        // ---- message values ----
        float m[4][4];   // [tn][r]
        #pragma unroll
        for (int r = 0; r < 4; ++r) {
            m[0][r] = silu_f(d2[0][r] + wbv[0]) * hv4[r].x;
            m[1][r] = silu_f(d2[1][r] + wbv[1]) * hv4[r].y;
            m[2][r] = silu_f(d2[2][r] + wbv[2]) * hv4[r].z;
            m[3][r] = silu_f(d2[3][r] + wbv[3]) * hv4[r].w;
        }

        // ---- segment handling ----
        if (rF == rL) {
            if (rF != curR) { flush(); curR = rF; }
            #pragma unroll
            for (int tn = 0; tn < 4; ++tn)
                accv[tn] += (m[tn][0] + m[tn][1]) + (m[tn][2] + m[tn][3]);
        } else {
            flush();
            curR = -1;
            int ridv[4];
            #pragma unroll
            for (int r = 0; r < 4; ++r)
                ridv[r] = __shfl(r_own, b16 + lg * 4 + r, 64);
            float a0 = m[0][0], a1 = m[1][0], a2 = m[2][0], a3 = m[3][0];
            int segR = ridv[0];
            #pragma unroll
            for (int r = 1; r < 4; ++r) {
                if (ridv[r] != segR) {
                    atomicAdd(&zt[segR * 64 +  0 + cr], a0);
                    atomicAdd(&zt[segR * 64 + 16 + cr], a1);
                    atomicAdd(&zt[segR * 64 + 32 + cr], a2);
                    atomicAdd(&zt[segR * 64 + 48 + cr], a3);
                    a0 = m[0][r]; a1 = m[1][r]; a2 = m[2][r]; a3 = m[3][r];
                    segR = ridv[r];
                } else {
                    a0 += m[0][r]; a1 += m[1][r]; a2 += m[2][r]; a3 += m[3][r];
                }
            }
            atomicAdd(&zt[segR * 64 +  0 + cr], a0);
            atomicAdd(&zt[segR * 64 + 16 + cr], a1);
            atomicAdd(&zt[segR * 64 + 32 + cr], a2);
            atomicAdd(&zt[segR * 64 + 48 + cr], a3);
        }
    }
    flush();
}

// ---------------- final kernel: g-subnets + residual ----------------
__global__ __launch_bounds__(128)
void final_kernel(const float* __restrict__ elec, const float* __restrict__ z,
                  const float* __restrict__ gWres, const float* __restrict__ gbres,
                  const float* __restrict__ gWz, const float* __restrict__ gbz,
                  float* __restrict__ out)
{
    __shared__ float xe[4 * 128];
    __shared__ float xz[3 * 4 * 64];
    int b = blockIdx.x;
    int tid = threadIdx.x;
    int row0 = b * 4;
    for (int i = tid; i < 4 * 128; i += 128)
        xe[i] = elec[row0 * 128 + i];
    for (int i = tid; i < 3 * 4 * 64; i += 128) {
        int t = i >> 8; int rr = (i >> 6) & 3; int k = i & 63;
        xz[i] = z[t * N_ELx * 64 + (row0 + rr) * 64 + k];
    }
    __syncthreads();

    int col = tid;
    float accr[4] = {0.f, 0.f, 0.f, 0.f};
    for (int k = 0; k < 128; ++k) {
        float wv = gWres[k * 128 + col];
        #pragma unroll
        for (int r = 0; r < 4; ++r) accr[r] += xe[r * 128 + k] * wv;
    }
    float o[4];
    float br = gbres[col];
    #pragma unroll
    for (int r = 0; r < 4; ++r) o[r] = silu_f(accr[r] + br) + xe[r * 128 + col];

    for (int t = 0; t < 3; ++t) {
        float accz[4] = {0.f, 0.f, 0.f, 0.f};
        for (int k = 0; k < 64; ++k) {
            float wv = gWz[(t * 64 + k) * 128 + col];
            #pragma unroll
            for (int r = 0; r < 4; ++r) accz[r] += xz[t * 256 + r * 64 + k] * wv;
        }
        float bz = gbz[t * 128 + col];
        #pragma unroll
        for (int r = 0; r < 4; ++r) o[r] += silu_f(accz[r] + bz);
    }
    #pragma unroll
    for (int r = 0; r < 4; ++r) out[(row0 + r) * 128 + col] = o[r];
}

extern "C" void kernel_launch(void* const* d_in, const int* in_sizes, int n_in,
                              void* d_out, int out_size, void* d_ws, size_t ws_size,
                              hipStream_t stream)
{
    const float* elec   = (const float*)d_in[0];
    const float* nuclei = (const float*)d_in[1];
    const float* feat0  = (const float*)d_in[2];
    const float* feat1  = (const float*)d_in[3];
    const float* feat2  = (const float*)d_in[4];
    const int*   s0     = (const int*)d_in[5];
    const int*   r0     = (const int*)d_in[6];
    const int*   s1     = (const int*)d_in[7];
    const int*   r1     = (const int*)d_in[8];
    const int*   s2     = (const int*)d_in[9];
    const int*   r2     = (const int*)d_in[10];
    const float* u_W    = (const float*)d_in[11];
    const float* u_b    = (const float*)d_in[12];
    const float* w_W    = (const float*)d_in[13];
    const float* w_b    = (const float*)d_in[14];
    const float* hWee   = (const float*)d_in[15];
    const float* hbee   = (const float*)d_in[16];
    const float* hWne   = (const float*)d_in[17];
    const float* hbne   = (const float*)d_in[18];
    const float* gWres  = (const float*)d_in[19];
    const float* gbres  = (const float*)d_in[20];
    const float* gWz    = (const float*)d_in[21];
    const float* gbz    = (const float*)d_in[22];
    float* out = (float*)d_out;

    char* ws = (char*)d_ws;
    float* hx0      = (float*)(ws + 0);           // 196608
    float* hx1      = (float*)(ws + 196608);      // 196608
    float* hxn      = (float*)(ws + 393216);      // 8192
    float* z        = (float*)(ws + 401408);      // 589824
    short* ufragT   = (short*)(ws + 991232);      // 12288
    short* wWfrag   = (short*)(ws + 1003520);     // 24576
    int*   binTotal = (int*)(ws + 1028096);       // 9216
    int*   perm     = (int*)(ws + 1046528);       // 2454528 (end 3501056)
    int*   blockHist= (int*)(ws + 3501056);       // 884736  (end 4385792)

    int n0 = in_sizes[2] / EDGE_INx;
    int n1 = in_sizes[3] / EDGE_INx;
    int n2 = in_sizes[4] / EDGE_INx;
    int nb0 = (n0 + EPB - 1) / EPB;
    int nb1 = (n1 + EPB - 1) / EPB;
    int nb2 = (n2 + EPB - 1) / EPB;

    setup_kernel<<<SETUP_FIXED, 256, 0, stream>>>(
        elec, nuclei, u_W, w_W, hWee, hbee, hWne, hbne,
        hx0, hx1, hxn, ufragT, wWfrag,
        r0, r1, r2, n0, n1, n2, blockHist, z);
    binscan_kernel<<<NBINS / 4, 256, 0, stream>>>(blockHist, binTotal);
    scatter2_kernel<<<NB_SORT, 256, 0, stream>>>(r0, r1, r2, n0, n1, n2,
                                                 blockHist, binTotal, perm);
    edge_kernel<<<nb0 + nb1 + nb2, 256, 0, stream>>>(
        feat0, feat1, feat2, s0, s1, s2, r0, r1, r2,
        u_b, w_b, hx0, hx1, hxn, ufragT, wWfrag, perm, z,
        n0, n1, n2, nb0, nb1);
    final_kernel<<<192, 128, 0, stream>>>(elec, z, gWres, gbres, gWz, gbz, out);
}

// Round 15
// 87.362 us; speedup vs baseline: 1.3618x; 1.0608x over previous
//
#include <hip/hip_runtime.h>
#include <hip/hip_bf16.h>
#include <stdint.h>

#define N_ELx 768
#define EMBx 128
#define TPSx 64
#define EDGE_INx 32
#define EPB 256            // edges per block (4 waves x 64)
#define NBINS 2304         // 3 types * 768 receivers
#define NB_SORT 96
#define SETUP_FIXED 110    // 14 prep + 96 hist blocks

typedef __attribute__((ext_vector_type(8))) short bf16x8;
typedef __attribute__((ext_vector_type(4))) float f32x4;
typedef __attribute__((ext_vector_type(4))) uint32_t u32x4;
typedef __attribute__((ext_vector_type(2))) uint32_t u32x2;

__device__ __forceinline__ short f2bf(float f) {
    union { float f; uint32_t u; } v; v.f = f;
    uint32_t u = v.u;
    uint32_t r = (u + 0x7FFFu + ((u >> 16) & 1u)) >> 16;
    return (short)r;
}

// 1-instruction packed f32->bf16 pair (lo -> low16, hi -> high16), RNE
__device__ __forceinline__ uint32_t cvtpk(float lo, float hi) {
    uint32_t r;
    asm("v_cvt_pk_bf16_f32 %0, %1, %2" : "=v"(r) : "v"(lo), "v"(hi));
    return r;
}

__device__ __forceinline__ bf16x8 mk8(uint32_t a, uint32_t b, uint32_t c, uint32_t d) {
    union { u32x4 u; bf16x8 h; } x;
    x.u = (u32x4){a, b, c, d};
    return x.h;
}

// fast silu: avoids fp32 div sequence
__device__ __forceinline__ float silu_f(float x) {
    float e = __builtin_amdgcn_exp2f(-1.442695041f * x);
    return x * __builtin_amdgcn_rcpf(1.0f + e);
}

// ---- setup kernel: prep (blocks 0..13) + blockhist (14..109) ----------------
// hx tables written TRANSPOSED within each row: hx[id][cr][tn] so edge's
// epilogue reads one float4 per (id,cr).
__global__ __launch_bounds__(256)
void setup_kernel(const float* __restrict__ elec, const float* __restrict__ nuclei,
                  const float* __restrict__ uW, const float* __restrict__ wW,
                  const float* __restrict__ hWee, const float* __restrict__ hbee,
                  const float* __restrict__ hWne, const float* __restrict__ hbne,
                  float* __restrict__ hx0, float* __restrict__ hx1, float* __restrict__ hxn,
                  short* __restrict__ ufragT, short* __restrict__ wWfrag,
                  const int* __restrict__ r0, const int* __restrict__ r1,
                  const int* __restrict__ r2,
                  int n0, int n1, int n2, int* __restrict__ blockHist,
                  float* __restrict__ z)
{
    __shared__ __align__(16) char smem[32768];
    int b = blockIdx.x;
    int tid = threadIdx.x;
    if (b < 12) {
        short* lds_a = (short*)smem;   // [kk*4+kc][row][8]
        int t = b / 6, rb = b % 6;
        const float* W = hWee + t * (128 * 64);
        {
            int row = tid >> 1, half = tid & 1;
            const float4* src = (const float4*)(elec + (size_t)(rb * 128 + row) * 128 + half * 64);
            #pragma unroll
            for (int c = 0; c < 8; ++c) {
                float4 fa = src[c * 2 + 0], fb = src[c * 2 + 1];
                bf16x8 v;
                v[0] = f2bf(fa.x); v[1] = f2bf(fa.y); v[2] = f2bf(fa.z); v[3] = f2bf(fa.w);
                v[4] = f2bf(fb.x); v[5] = f2bf(fb.y); v[6] = f2bf(fb.z); v[7] = f2bf(fb.w);
                int kk = half * 2 + (c >> 2), kc = c & 3;
                *(bf16x8*)&lds_a[((kk * 4 + kc) * 128 + row) * 8] = v;
            }
        }
        __syncthreads();
        int lane = tid & 63, w = tid >> 6, kc = lane >> 4, cr = lane & 15;
        int col = w * 16 + cr;
        bf16x8 bfrag[4];
        #pragma unroll
        for (int kk = 0; kk < 4; ++kk) {
            bf16x8 v;
            #pragma unroll
            for (int j = 0; j < 8; ++j)
                v[j] = f2bf(W[(kk * 32 + kc * 8 + j) * 64 + col]);
            bfrag[kk] = v;
        }
        float bias = hbee[t * 64 + col];
        float* dst = (t == 0 ? hx0 : hx1);
        f32x4 zero4 = {0.f, 0.f, 0.f, 0.f};
        #pragma unroll
        for (int rt = 0; rt < 8; ++rt) {
            f32x4 acc = zero4;
            #pragma unroll
            for (int kk = 0; kk < 4; ++kk) {
                bf16x8 a = *(const bf16x8*)&lds_a[((kk * 4 + kc) * 128 + rt * 16 + cr) * 8];
                acc = __builtin_amdgcn_mfma_f32_16x16x32_bf16(a, bfrag[kk], acc, 0, 0, 0);
            }
            #pragma unroll
            for (int r = 0; r < 4; ++r) {
                int row = rb * 128 + rt * 16 + kc * 4 + r;
                dst[row * 64 + cr * 4 + w] = silu_f(acc[r] + bias);   // transposed
            }
        }
    } else if (b == 12) {
        // hxn: silu(nuclei @ hWne + hbne), transposed write
        int lr = tid >> 6, col = tid & 63;
        for (int i = 0; i < 8; ++i) {
            int row = lr * 8 + i;
            float acc = 0.f;
            for (int k = 0; k < 64; ++k)
                acc += nuclei[row * 64 + k] * hWne[k * 64 + col];
            hxn[row * 64 + (col & 15) * 4 + (col >> 4)] = silu_f(acc + hbne[col]);
        }
    } else if (b == 13) {
        // ufragT: A-fragment of uW^T: A[ucol=tr*16+cr][k=featcol=lg*8+j]
        for (int idx = tid; idx < 3 * 4 * 64; idx += 256) {
            int lane = idx & 63, tr = (idx >> 6) & 3, ty = idx >> 8;
            int lg = lane >> 4, cr = lane & 15;
            for (int j = 0; j < 8; ++j)
                ufragT[idx * 8 + j] =
                    f2bf(uW[(ty * EDGE_INx + lg * 8 + j) * TPSx + tr * 16 + cr]);
        }
        // wWfrag: B-fragment of wW: B[k=ks*32+lg*8+j][col=tn*16+cr]
        for (int idx = tid; idx < 3 * 2 * 4 * 64; idx += 256) {
            int lane = idx & 63, ct = (idx >> 6) & 3, ks = (idx >> 8) & 1, ty = idx >> 9;
            for (int j = 0; j < 8; ++j) {
                int k = ks * 32 + (lane >> 4) * 8 + j, col = ct * 16 + (lane & 15);
                wWfrag[idx * 8 + j] = f2bf(wW[(ty * 64 + k) * 64 + col]);
            }
        }
    } else {
        // blockhist for sort + fold-in z zeroing
        int* h = (int*)smem;
        int bb = b - 14;                         // 0..95
        for (int i = bb * 256 + tid; i < 3 * N_ELx * TPSx; i += NB_SORT * 256)
            z[i] = 0.f;
        for (int i = tid; i < NBINS; i += 256) h[i] = 0;
        __syncthreads();
        int total = n0 + n1 + n2;
        int chunk = (total + NB_SORT - 1) / NB_SORT;
        int start = bb * chunk, end = min(start + chunk, total);
        for (int i = start + tid; i < end; i += 256) {
            int t, j;
            if (i < n0)            { t = 0; j = i; }
            else if (i < n0 + n1)  { t = 1; j = i - n0; }
            else                   { t = 2; j = i - n0 - n1; }
            int rv = (t == 0 ? r0 : (t == 1 ? r1 : r2))[j];
            atomicAdd(&h[t * 768 + rv], 1);
        }
        __syncthreads();
        for (int i = tid; i < NBINS; i += 256)
            blockHist[i * NB_SORT + bb] = h[i];
    }
}

// ---------------- sort: wave-per-bin parallel scan (96 entries) --------------
__global__ __launch_bounds__(256)
void binscan_kernel(int* __restrict__ blockHist, int* __restrict__ binTotal)
{
    int tid = threadIdx.x;
    int w = tid >> 6, lane = tid & 63;
    int bin = blockIdx.x * 4 + w;            // grid = NBINS/4 = 576
    int* p = blockHist + bin * NB_SORT;      // 96 entries
    int a = p[lane];
    int bv = (lane < 32) ? p[64 + lane] : 0;
    int a0 = a, b0 = bv;
    #pragma unroll
    for (int d = 1; d < 64; d <<= 1) {
        int tv = __shfl_up(a, d, 64);
        if (lane >= d) a += tv;
    }
    int sumA = __shfl(a, 63, 64);
    #pragma unroll
    for (int d = 1; d < 32; d <<= 1) {
        int tv = __shfl_up(bv, d, 64);
        if (lane >= d) bv += tv;
    }
    p[lane] = a - a0;                        // exclusive
    if (lane < 32) p[64 + lane] = sumA + bv - b0;
    if (lane == 31) binTotal[bin] = sumA + bv;
}

// 512 threads: first 256 build the cursor (scan), all 512 scatter.
__global__ __launch_bounds__(512)
void scatter2_kernel(const int* __restrict__ r0, const int* __restrict__ r1,
                     const int* __restrict__ r2,
                     int n0, int n1, int n2,
                     const int* __restrict__ blockHist,
                     const int* __restrict__ binTotal,
                     int* __restrict__ perm)
{
    __shared__ int cursor[NBINS];
    __shared__ int part[256];
    int tid = threadIdx.x, b = blockIdx.x;
    if (tid < 256) {
        int l[9]; int s = 0;
        #pragma unroll
        for (int j = 0; j < 9; ++j) { l[j] = binTotal[tid * 9 + j]; s += l[j]; }
        part[tid] = s;
        __syncthreads();
        for (int off = 1; off < 256; off <<= 1) {
            int v = (tid >= off) ? part[tid - off] : 0;
            __syncthreads();
            part[tid] += v;
            __syncthreads();
        }
        int run = (tid == 0) ? 0 : part[tid - 1];
        #pragma unroll
        for (int j = 0; j < 9; ++j) {
            int bin = tid * 9 + j;
            cursor[bin] = run + blockHist[bin * NB_SORT + b];
            run += l[j];
        }
    } else {
        // participate in the same barrier sequence as the scan branch
        __syncthreads();
        for (int off = 1; off < 256; off <<= 1) {
            __syncthreads();
            __syncthreads();
        }
    }
    __syncthreads();
    int total = n0 + n1 + n2;
    int chunk = (total + NB_SORT - 1) / NB_SORT;
    int start = b * chunk, end = min(start + chunk, total);
    for (int i = start + tid; i < end; i += 512) {
        int t, j;
        if (i < n0)            { t = 0; j = i; }
        else if (i < n0 + n1)  { t = 1; j = i - n0; }
        else                   { t = 2; j = i - n0 - n1; }
        int rv = (t == 0 ? r0 : (t == 1 ? r1 : r2))[j];
        int pos = atomicAdd(&cursor[t * 768 + rv], 1);
        perm[pos] = j;
    }
}

// ---- edge kernel: LDS weights + depth-2 feat prefetch -----------------------
__global__ __launch_bounds__(256)
void edge_kernel(const float* __restrict__ feat0, const float* __restrict__ feat1,
                 const float* __restrict__ feat2,
                 const int* __restrict__ s0, const int* __restrict__ s1, const int* __restrict__ s2,
                 const int* __restrict__ r0, const int* __restrict__ r1, const int* __restrict__ r2,
                 const float* __restrict__ u_b, const float* __restrict__ w_b,
                 const float* __restrict__ hx0, const float* __restrict__ hx1,
                 const float* __restrict__ hxn,
                 const short* __restrict__ ufragT, const short* __restrict__ wWfrag,
                 const int* __restrict__ perm,
                 float* __restrict__ z,
                 int n0, int n1, int n2, int nb0, int nb1)
{
    __shared__ __align__(16) short wt_lds[12 * 64 * 8];     // uf 4KB | wf 8KB
    __shared__ __align__(16) char ebuf_all[4][16 * 144];    // 2304B per wave

    int b = blockIdx.x;
    int t; const float* feat; const int* sn; const int* rc; const float* hx; int nE;
    if (b < nb0)            { t = 0; feat = feat0; sn = s0; rc = r0; hx = hx0; nE = n0; }
    else if (b < nb0 + nb1) { t = 1; b -= nb0; feat = feat1; sn = s1; rc = r1; hx = hx1; nE = n1; }
    else                    { t = 2; b -= nb0 + nb1; feat = feat2; sn = s2; rc = r2; hx = hxn; nE = n2; }

    int tid = threadIdx.x;
    int w = tid >> 6, lane = tid & 63, lg = lane >> 4, cr = lane & 15;
    int ebase = b * EPB + w * 64;

    // stage weight fragments (shared by the block's 4 waves), then barrier
    {
        const short* usrc = ufragT + t * (4 * 64 * 8);
        *(bf16x8*)&wt_lds[tid * 8] = *(const bf16x8*)&usrc[tid * 8];
        const short* wsrc = wWfrag + t * (2 * 4 * 64 * 8);
        *(bf16x8*)&wt_lds[(256 + tid) * 8] = *(const bf16x8*)&wsrc[tid * 8];
        *(bf16x8*)&wt_lds[(512 + tid) * 8] = *(const bf16x8*)&wsrc[(256 + tid) * 8];
    }
    __syncthreads();
    if (ebase >= nE) return;                    // no barriers after this point
    bool partial = (ebase + 64 > nE);           // never true: all counts divide 256
    char* ebuf = ebuf_all[w];
    int t_off = (t == 0) ? 0 : (t == 1 ? n0 : n0 + n1);
    float* zt = z + t * (N_ELx * TPSx);

    // biases in registers (20)
    float4 ubv[4];
    #pragma unroll
    for (int tr = 0; tr < 4; ++tr)
        ubv[tr] = *(const float4*)(u_b + t * 64 + tr * 16 + lg * 4);
    float wbv[4];
    #pragma unroll
    for (int tn = 0; tn < 4; ++tn)
        wbv[tn] = w_b[t * 64 + tn * 16 + cr];

    // own-edge meta: lane owns edge ebase + lane
    int e_own = ebase + lane;
    int pe_own = perm[t_off + min(e_own, nE - 1)];
    int s_own = sn[pe_own];
    int r_own = rc[pe_own];

    f32x4 zero4 = {0.f, 0.f, 0.f, 0.f};

    // deferred segment accumulator
    float accv[4] = {0.f, 0.f, 0.f, 0.f};
    int curR = -1;
    auto flush = [&]() {
        if (curR >= 0) {
            #pragma unroll
            for (int tn = 0; tn < 4; ++tn) {
                float v = accv[tn];
                v += __shfl_xor(v, 16, 64);
                v += __shfl_xor(v, 32, 64);
                if (lg == 0) atomicAdd(&zt[curR * 64 + tn * 16 + cr], v);
                accv[tn] = 0.f;
            }
        }
    };

    // ---- depth-2 feat prefetch (tiles 0,1 in prologue; tc+2 inside body) ----
    int pFa[4];
    #pragma unroll
    for (int tc = 0; tc < 4; ++tc)
        pFa[tc] = __shfl(pe_own, tc * 16 + cr, 64);
    float4 fav[4], fcv[4];
    #pragma unroll
    for (int tc = 0; tc < 2; ++tc) {
        const float4* fp = (const float4*)(feat + (size_t)pFa[tc] * EDGE_INx + lg * 8);
        fav[tc] = fp[0]; fcv[tc] = fp[1];
    }

    #pragma unroll
    for (int tc = 0; tc < 4; ++tc) {
        int b16 = tc * 16;

        // prefetch tile tc+2
        if (tc < 2) {
            const float4* fp = (const float4*)(feat + (size_t)pFa[tc + 2] * EDGE_INx + lg * 8);
            fav[tc + 2] = fp[0]; fcv[tc + 2] = fp[1];
        }

        // ---- per-tile meta via shfl; issue hx gathers (float4) early ----
        int sidv[4];
        #pragma unroll
        for (int r = 0; r < 4; ++r)
            sidv[r] = __shfl(s_own, b16 + lg * 4 + r, 64);
        int rF = __shfl(r_own, b16, 64);
        int rL = __shfl(r_own, b16 + 15, 64);

        float4 hv4[4];   // [r] -> (tn=0..3), via transposed hx layout
        if (!partial) {
            #pragma unroll
            for (int r = 0; r < 4; ++r)
                hv4[r] = ((const float4*)(hx + sidv[r] * TPSx))[cr];
        } else {
            #pragma unroll
            for (int r = 0; r < 4; ++r) {
                bool aE = (ebase + b16 + lg * 4 + r) < nE;
                hv4[r] = aE ? ((const float4*)(hx + sidv[r] * TPSx))[cr]
                            : make_float4(0.f, 0.f, 0.f, 0.f);
            }
        }

        // ---- feat B-frag from prefetched regs ----
        float4 fa = fav[tc], fc = fcv[tc];
        bf16x8 fB = mk8(cvtpk(fa.x, fa.y), cvtpk(fa.z, fa.w),
                        cvtpk(fc.x, fc.y), cvtpk(fc.z, fc.w));

        // ---- GEMM1: e^T tiles (uf read from LDS, lane-invariant addr) ----
        f32x4 d1[4];
        #pragma unroll
        for (int tr = 0; tr < 4; ++tr) {
            bf16x8 a = *(const bf16x8*)&wt_lds[(tr * 64 + lane) * 8];
            d1[tr] = __builtin_amdgcn_mfma_f32_16x16x32_bf16(a, fB, zero4, 0, 0, 0);
        }

        // ---- silu + pack + per-wave LDS transpose write ----
        #pragma unroll
        for (int tr = 0; tr < 4; ++tr) {
            float v0 = silu_f(d1[tr][0] + ubv[tr].x);
            float v1 = silu_f(d1[tr][1] + ubv[tr].y);
            float v2 = silu_f(d1[tr][2] + ubv[tr].z);
            float v3 = silu_f(d1[tr][3] + ubv[tr].w);
            u32x2 pk; pk[0] = cvtpk(v0, v1); pk[1] = cvtpk(v2, v3);
            *(u32x2*)(ebuf + cr * 144 + tr * 32 + lg * 8) = pk;
        }

        // ---- read A-frags of e (same-wave DS ordering: no barrier) ----
        bf16x8 ebf0 = *(const bf16x8*)(ebuf + cr * 144 + 0 * 64 + lg * 16);
        bf16x8 ebf1 = *(const bf16x8*)(ebuf + cr * 144 + 1 * 64 + lg * 16);

        // ---- GEMM2: we tiles (wf read from LDS) ----
        f32x4 d2[4];
        #pragma unroll
        for (int tn = 0; tn < 4; ++tn) {
            bf16x8 w0 = *(const bf16x8*)&wt_lds[(256 + tn * 64 + lane) * 8];
            bf16x8 w1 = *(const bf16x8*)&wt_lds[(256 + (4 + tn) * 64 + lane) * 8];
            f32x4 acc = __builtin_amdgcn_mfma_f32_16x16x32_bf16(ebf0, w0, zero4, 0, 0, 0);
            d2[tn] = __builtin_amdgcn_mfma_f32_16x16x32_bf16(ebf1, w1, acc, 0, 0, 0);
        }

        // ---- message values ----
        float m[4][4];   // [tn][r]
        #pragma unroll
        for (int r = 0; r < 4; ++r) {
            m[0][r] = silu_f(d2[0][r] + wbv[0]) * hv4[r].x;
            m[1][r] = silu_f(d2[1][r] + wbv[1]) * hv4[r].y;
            m[2][r] = silu_f(d2[2][r] + wbv[2]) * hv4[r].z;
            m[3][r] = silu_f(d2[3][r] + wbv[3]) * hv4[r].w;
        }

        // ---- segment handling ----
        if (rF == rL) {
            if (rF != curR) { flush(); curR = rF; }
            #pragma unroll
            for (int tn = 0; tn < 4; ++tn)
                accv[tn] += (m[tn][0] + m[tn][1]) + (m[tn][2] + m[tn][3]);
        } else {
            flush();
            curR = -1;
            int ridv[4];
            #pragma unroll
            for (int r = 0; r < 4; ++r)
                ridv[r] = __shfl(r_own, b16 + lg * 4 + r, 64);
            float a0 = m[0][0], a1 = m[1][0], a2 = m[2][0], a3 = m[3][0];
            int segR = ridv[0];
            #pragma unroll
            for (int r = 1; r < 4; ++r) {
                if (ridv[r] != segR) {
                    atomicAdd(&zt[segR * 64 +  0 + cr], a0);
                    atomicAdd(&zt[segR * 64 + 16 + cr], a1);
                    atomicAdd(&zt[segR * 64 + 32 + cr], a2);
                    atomicAdd(&zt[segR * 64 + 48 + cr], a3);
                    a0 = m[0][r]; a1 = m[1][r]; a2 = m[2][r]; a3 = m[3][r];
                    segR = ridv[r];
                } else {
                    a0 += m[0][r]; a1 += m[1][r]; a2 += m[2][r]; a3 += m[3][r];
                }
            }
            atomicAdd(&zt[segR * 64 +  0 + cr], a0);
            atomicAdd(&zt[segR * 64 + 16 + cr], a1);
            atomicAdd(&zt[segR * 64 + 32 + cr], a2);
            atomicAdd(&zt[segR * 64 + 48 + cr], a3);
        }
    }
    flush();
}

// ---------------- final kernel: g-subnets + residual (256 blocks, 3 rows) ----
__global__ __launch_bounds__(128)
void final_kernel(const float* __restrict__ elec, const float* __restrict__ z,
                  const float* __restrict__ gWres, const float* __restrict__ gbres,
                  const float* __restrict__ gWz, const float* __restrict__ gbz,
                  float* __restrict__ out)
{
    __shared__ float xe[3 * 128];
    __shared__ float xz[3 * 3 * 64];
    int b = blockIdx.x;     // 0..255
    int tid = threadIdx.x;  // 0..127
    int row0 = b * 3;
    for (int i = tid; i < 3 * 128; i += 128)
        xe[i] = elec[row0 * 128 + i];
    for (int i = tid; i < 3 * 3 * 64; i += 128) {
        int t = i / 192; int rr = (i / 64) % 3; int k = i % 64;
        xz[i] = z[t * N_ELx * 64 + (row0 + rr) * 64 + k];
    }
    __syncthreads();

    int col = tid;
    float accr[3] = {0.f, 0.f, 0.f};
    #pragma unroll 8
    for (int k = 0; k < 128; ++k) {
        float wv = gWres[k * 128 + col];
        #pragma unroll
        for (int r = 0; r < 3; ++r) accr[r] += xe[r * 128 + k] * wv;
    }
    float o[3];
    float br = gbres[col];
    #pragma unroll
    for (int r = 0; r < 3; ++r) o[r] = silu_f(accr[r] + br) + xe[r * 128 + col];

    for (int t = 0; t < 3; ++t) {
        float accz[3] = {0.f, 0.f, 0.f};
        #pragma unroll 8
        for (int k = 0; k < 64; ++k) {
            float wv = gWz[(t * 64 + k) * 128 + col];
            #pragma unroll
            for (int r = 0; r < 3; ++r) accz[r] += xz[t * 192 + r * 64 + k] * wv;
        }
        float bz = gbz[t * 128 + col];
        #pragma unroll
        for (int r = 0; r < 3; ++r) o[r] += silu_f(accz[r] + bz);
    }
    #pragma unroll
    for (int r = 0; r < 3; ++r) out[(row0 + r) * 128 + col] = o[r];
}

extern "C" void kernel_launch(void* const* d_in, const int* in_sizes, int n_in,
                              void* d_out, int out_size, void* d_ws, size_t ws_size,
                              hipStream_t stream)
{
    const float* elec   = (const float*)d_in[0];
    const float* nuclei = (const float*)d_in[1];
    const float* feat0  = (const float*)d_in[2];
    const float* feat1  = (const float*)d_in[3];
    const float* feat2  = (const float*)d_in[4];
    const int*   s0     = (const int*)d_in[5];
    const int*   r0     = (const int*)d_in[6];
    const int*   s1     = (const int*)d_in[7];
    const int*   r1     = (const int*)d_in[8];
    const int*   s2     = (const int*)d_in[9];
    const int*   r2     = (const int*)d_in[10];
    const float* u_W    = (const float*)d_in[11];
    const float* u_b    = (const float*)d_in[12];
    const float* w_W    = (const float*)d_in[13];
    const float* w_b    = (const float*)d_in[14];
    const float* hWee   = (const float*)d_in[15];
    const float* hbee   = (const float*)d_in[16];
    const float* hWne   = (const float*)d_in[17];
    const float* hbne   = (const float*)d_in[18];
    const float* gWres  = (const float*)d_in[19];
    const float* gbres  = (const float*)d_in[20];
    const float* gWz    = (const float*)d_in[21];
    const float* gbz    = (const float*)d_in[22];
    float* out = (float*)d_out;

    char* ws = (char*)d_ws;
    float* hx0      = (float*)(ws + 0);           // 196608
    float* hx1      = (float*)(ws + 196608);      // 196608
    float* hxn      = (float*)(ws + 393216);      // 8192
    float* z        = (float*)(ws + 401408);      // 589824
    short* ufragT   = (short*)(ws + 991232);      // 12288
    short* wWfrag   = (short*)(ws + 1003520);     // 24576
    int*   binTotal = (int*)(ws + 1028096);       // 9216
    int*   perm     = (int*)(ws + 1046528);       // 2454528 (end 3501056)
    int*   blockHist= (int*)(ws + 3501056);       // 884736  (end 4385792)

    int n0 = in_sizes[2] / EDGE_INx;
    int n1 = in_sizes[3] / EDGE_INx;
    int n2 = in_sizes[4] / EDGE_INx;
    int nb0 = (n0 + EPB - 1) / EPB;
    int nb1 = (n1 + EPB - 1) / EPB;
    int nb2 = (n2 + EPB - 1) / EPB;

    setup_kernel<<<SETUP_FIXED, 256, 0, stream>>>(
        elec, nuclei, u_W, w_W, hWee, hbee, hWne, hbne,
        hx0, hx1, hxn, ufragT, wWfrag,
        r0, r1, r2, n0, n1, n2, blockHist, z);
    binscan_kernel<<<NBINS / 4, 256, 0, stream>>>(blockHist, binTotal);
    scatter2_kernel<<<NB_SORT, 512, 0, stream>>>(r0, r1, r2, n0, n1, n2,
                                                 blockHist, binTotal, perm);
    edge_kernel<<<nb0 + nb1 + nb2, 256, 0, stream>>>(
        feat0, feat1, feat2, s0, s1, s2, r0, r1, r2,
        u_b, w_b, hx0, hx1, hxn, ufragT, wWfrag, perm, z,
        n0, n1, n2, nb0, nb1);
    final_kernel<<<256, 128, 0, stream>>>(elec, z, gWres, gbres, gWz, gbz, out);
}